// Round 1
// baseline (495.192 us; speedup 1.0000x reference)
//
#include <hip/hip_runtime.h>

typedef unsigned short u16;
typedef __attribute__((ext_vector_type(8))) short short8;
typedef __attribute__((ext_vector_type(4))) float f32x4;

constexpr int B_N    = 2;
constexpr int SEQ    = 1024;
constexpr int DMODEL = 768;
constexpr int DINNER = 1536;
constexpr int NH     = 24;
constexpr int DMLP   = 1920;
constexpr int NPROJ  = 6936;
constexpr int PP     = 7040;          // padded proj width (55*128)
constexpr int MROWS  = B_N * SEQ;     // 2048
constexpr int NCHUNK = 16;
constexpr int CLEN   = 64;

__device__ __forceinline__ u16 f2bf(float f) {
  union { float f; unsigned u; } x; x.f = f;
  unsigned r = x.u + 0x7fffu + ((x.u >> 16) & 1u);
  return (u16)(r >> 16);
}

__device__ __forceinline__ void gld_lds16(const u16* g, u16* l) {
  __builtin_amdgcn_global_load_lds((const __attribute__((address_space(1))) void*)g,
                                   (__attribute__((address_space(3))) void*)l, 16, 0, 0);
}

// ---------------- weight cast (f32 -> bf16, optional row pad with zeros) ----
__global__ void cast_w_kernel(const float* __restrict__ src, u16* __restrict__ dst,
                              int src_rows, int cols, int total) {
  int i = blockIdx.x * 256 + threadIdx.x;
  if (i >= total) return;
  int n = i / cols;
  int k = i - n * cols;
  float v = (n < src_rows) ? src[(size_t)n * cols + k] : 0.f;
  dst[i] = f2bf(v);
}

// ---------------- fused (a [+ b]) -> rmsnorm -> bf16 ; optional raw-sum out --
__global__ __launch_bounds__(256) void add_rmsnorm_kernel(
    const float* __restrict__ a, const float* __restrict__ b,
    const float* __restrict__ w, float* __restrict__ sum_out,
    u16* __restrict__ hout) {
  int row = blockIdx.x;
  int t = threadIdx.x;
  const float* pa = a + (size_t)row * DMODEL;
  const float* pb = b ? b + (size_t)row * DMODEL : nullptr;
  float v[3]; float ss = 0.f;
#pragma unroll
  for (int i = 0; i < 3; ++i) {
    int c = t + i * 256;
    float x = pa[c];
    if (pb) x += pb[c];
    v[i] = x; ss += x * x;
  }
#pragma unroll
  for (int o = 32; o > 0; o >>= 1) ss += __shfl_xor(ss, o);
  __shared__ float red[4];
  if ((t & 63) == 0) red[t >> 6] = ss;
  __syncthreads();
  ss = red[0] + red[1] + red[2] + red[3];
  float sc = rsqrtf(ss * (1.f / DMODEL) + 1e-5f);
#pragma unroll
  for (int i = 0; i < 3; ++i) {
    int c = t + i * 256;
    if (sum_out) sum_out[(size_t)row * DMODEL + c] = v[i];
    hout[(size_t)row * DMODEL + c] = f2bf(v[i] * sc * w[c]);
  }
}

// ---------------- bf16 MFMA GEMM: C(M x N, f32, ldc) = A(MxK) * B(NxK)^T ----
// grid = (N/128, M/128), block = 256 (4 waves, 2x2 of 64x64)
__global__ __launch_bounds__(256) void gemm_bt_kernel(
    const u16* __restrict__ A, const u16* __restrict__ Bw,
    float* __restrict__ C, int K, int ldc) {
  __shared__ u16 As[128 * 64];
  __shared__ u16 Bs[128 * 64];
  const int t = threadIdx.x;
  const int lane = t & 63;
  const int wave = t >> 6;
  const int wm = wave >> 1, wn = wave & 1;
  const int m0 = blockIdx.y * 128, n0 = blockIdx.x * 128;
  f32x4 acc[4][4] = {};
  const int rr = t >> 3;          // 0..31  (row within 32-row slab)
  const int kc = (t & 7) * 8;     // 0..56  (k element offset)
  const u16* ga = A + (size_t)(m0 + rr) * K + kc;
  const u16* gb = Bw + (size_t)(n0 + rr) * K + kc;
  for (int kt = 0; kt < K; kt += 64) {
    __syncthreads();
#pragma unroll
    for (int i = 0; i < 4; ++i) {
      gld_lds16(ga + (size_t)i * 32 * K + kt, As + i * 2048 + t * 8);
      gld_lds16(gb + (size_t)i * 32 * K + kt, Bs + i * 2048 + t * 8);
    }
    __syncthreads();
#pragma unroll
    for (int kh = 0; kh < 2; ++kh) {
      short8 af[4], bfr[4];
#pragma unroll
      for (int i = 0; i < 4; ++i)
        af[i] = *(const short8*)(As + (wm * 64 + i * 16 + (lane & 15)) * 64 + kh * 32 + (lane >> 4) * 8);
#pragma unroll
      for (int j = 0; j < 4; ++j)
        bfr[j] = *(const short8*)(Bs + (wn * 64 + j * 16 + (lane & 15)) * 64 + kh * 32 + (lane >> 4) * 8);
#pragma unroll
      for (int i = 0; i < 4; ++i)
#pragma unroll
        for (int j = 0; j < 4; ++j)
          acc[i][j] = __builtin_amdgcn_mfma_f32_16x16x32_bf16(af[i], bfr[j], acc[i][j], 0, 0, 0);
    }
  }
  const int cr = (lane >> 4) * 4;
  const int cc = lane & 15;
#pragma unroll
  for (int i = 0; i < 4; ++i) {
#pragma unroll
    for (int j = 0; j < 4; ++j) {
      int row = m0 + wm * 64 + i * 16 + cr;
      int col = n0 + wn * 64 + j * 16 + cc;
      float* cp = C + (size_t)row * ldc + col;
#pragma unroll
      for (int r = 0; r < 4; ++r) cp[(size_t)r * ldc] = acc[i][j][r];
    }
  }
}

// ---------------- prep: B/C rmsnorm+bias (in place), dt/alpha, skip, dtheta,
//                  pre-scale x_ssm by gamma. One wave per (m,h). ------------
__global__ __launch_bounds__(256) void prep_kernel(
    float* __restrict__ proj, const float* __restrict__ A_log,
    const float* __restrict__ Dv, const float* __restrict__ dt_bias,
    const float* __restrict__ B_bias, const float* __restrict__ C_bias,
    const float* __restrict__ Bnw, const float* __restrict__ Cnw,
    float* __restrict__ alpha_b, float* __restrict__ skip_b,
    float* __restrict__ dtheta) {
  int wid = blockIdx.x * 4 + (threadIdx.x >> 6);
  int lane = threadIdx.x & 63;
  int m = wid / NH, h = wid - m * NH;
  float* row = proj + (size_t)m * PP;

  float Braw = row[3072 + h * 64 + lane];
  float Craw = row[4608 + h * 64 + lane];
  float sb = Braw * Braw, sc2 = Craw * Craw;
#pragma unroll
  for (int o = 32; o > 0; o >>= 1) { sb += __shfl_xor(sb, o); sc2 += __shfl_xor(sc2, o); }
  float rb = rsqrtf(sb * (1.f / 64.f) + 1e-5f);
  float rc = rsqrtf(sc2 * (1.f / 64.f) + 1e-5f);
  row[3072 + h * 64 + lane] = Braw * rb * Bnw[lane] + B_bias[h * 64 + lane];
  row[4608 + h * 64 + lane] = Craw * rc * Cnw[lane] + C_bias[h * 64 + lane];

  float dtr = row[6144 + h] + dt_bias[h];
  float dt = dtr > 20.f ? dtr : log1pf(expf(dtr));
  float A = -expf(A_log[h]) * dt;
  float alpha = expf(A);
  float gamma = (alpha - 1.f) / (A + 1e-6f) * 0.5f + 1.f;

  float xv = row[1536 + h * 64 + lane];
  float sx = xv;
#pragma unroll
  for (int o = 32; o > 0; o >>= 1) sx += __shfl_xor(sx, o);
  row[1536 + h * 64 + lane] = xv * gamma;   // pre-scale for scan

  if (lane == 0) {
    alpha_b[(size_t)m * NH + h] = alpha;
    skip_b[(size_t)m * NH + h] = Dv[h] * sx;
  }
  if (lane < 32) {
    float th = row[6168 + h * 32 + lane];
    dtheta[(size_t)m * 768 + h * 32 + lane] = dt * th;
  }
}

// ---------------- cumsum of dtheta over s (1536 independent chains) --------
__global__ void cumsum_kernel(float* __restrict__ dtheta) {
  int tid = blockIdx.x * 256 + threadIdx.x;   // < 1536
  int b = tid / 768, col = tid - b * 768;
  float* p = dtheta + (size_t)b * SEQ * 768 + col;
  float acc = 0.f;
  for (int s = 0; s < SEQ; ++s) {
    acc += p[(size_t)s * 768];
    p[(size_t)s * 768] = acc;
  }
}

// ---------------- RoPE on B (lanes 0..31) and C (lanes 32..63), in place ----
__global__ __launch_bounds__(256) void rope_kernel(
    float* __restrict__ proj, const float* __restrict__ cумt_dummy, const float* __restrict__ cumt) {
  int wid = blockIdx.x * 4 + (threadIdx.x >> 6);
  int lane = threadIdx.x & 63;
  int m = wid / NH, h = wid - m * NH;
  int j = lane & 31;
  float ang = cumt[(size_t)m * 768 + h * 32 + j];
  float sn, cs;
  sincosf(ang, &sn, &cs);
  int base = (lane < 32) ? 3072 : 4608;
  float2* p = (float2*)(proj + (size_t)m * PP + base + h * 64) + j;
  float2 v = *p;
  float2 o; o.x = cs * v.x - sn * v.y; o.y = sn * v.x + cs * v.y;
  *p = o;
}

// ---------------- scan phase 1: intra-chunk scan from zero state -----------
// block = (bh, chunk); 4 waves: wave w owns n in [w*16,w*16+16), lane = p
__global__ __launch_bounds__(256) void scan1_kernel(
    const float* __restrict__ proj, const float* __restrict__ alpha_b,
    float* __restrict__ ybuf, float* __restrict__ Hbuf,
    float* __restrict__ cumdec) {
  int c = blockIdx.x & 15, bh = blockIdx.x >> 4;
  int b = bh / NH, h = bh - b * NH;
  int t = threadIdx.x, w = t >> 6, l = t & 63;
  __shared__ float sB[64], sC[64], sX[64], sAl;
  __shared__ float part[2][4][64];
  float hst[16];
#pragma unroll
  for (int j = 0; j < 16; ++j) hst[j] = 0.f;
  float cd = 1.f;
  int m0 = b * SEQ + c * CLEN;
  for (int s = 0; s < CLEN; ++s) {
    int m = m0 + s;
    const float* row = proj + (size_t)m * PP;
    if (t < 64)        sB[t] = row[3072 + h * 64 + t];
    else if (t < 128)  sC[t - 64] = row[4608 + h * 64 + (t - 64)];
    else if (t < 192)  sX[t - 128] = row[1536 + h * 64 + (t - 128)];
    else if (t == 192) sAl = alpha_b[(size_t)m * NH + h];
    __syncthreads();
    if (s > 0 && w == 0) {
      int pb = (s - 1) & 1;
      float ysum = part[pb][0][l] + part[pb][1][l] + part[pb][2][l] + part[pb][3][l];
      ybuf[(size_t)(m - 1) * DINNER + h * 64 + l] = ysum;
    }
    float a = sAl;
    float xp = sX[l];
    float ps = 0.f;
#pragma unroll
    for (int j = 0; j < 16; ++j) {
      hst[j] = hst[j] * a + sB[w * 16 + j] * xp;
      ps += hst[j] * sC[w * 16 + j];
    }
    part[s & 1][w][l] = ps;
    cd *= a;
    if (t == 0) cumdec[(size_t)m * NH + h] = cd;
    __syncthreads();
  }
  if (w == 0) {
    float ysum = part[1][0][l] + part[1][1][l] + part[1][2][l] + part[1][3][l];
    ybuf[(size_t)(m0 + CLEN - 1) * DINNER + h * 64 + l] = ysum;
  }
  float* Hp = Hbuf + ((size_t)(bh * NCHUNK + c)) * 4096 + l * 64 + w * 16;
#pragma unroll
  for (int j = 0; j < 16; j += 4) {
    float4 v; v.x = hst[j]; v.y = hst[j + 1]; v.z = hst[j + 2]; v.w = hst[j + 3];
    *(float4*)(Hp + j) = v;
  }
}

// ---------------- scan phase 2: chunk-level recurrence; Hbuf becomes H_in ---
__global__ __launch_bounds__(256) void scan2_kernel(
    float* __restrict__ Hbuf, const float* __restrict__ cumdec) {
  int bh = blockIdx.x;
  int b = bh / NH, h = bh - b * NH;
  int e = threadIdx.x * 16;
  float S[16];
#pragma unroll
  for (int j = 0; j < 16; ++j) S[j] = 0.f;
  for (int c = 0; c < NCHUNK; ++c) {
    float* Hp = Hbuf + ((size_t)(bh * NCHUNK + c)) * 4096 + e;
    float P = cumdec[(size_t)(b * SEQ + c * CLEN + CLEN - 1) * NH + h];
#pragma unroll
    for (int j = 0; j < 16; j += 4) {
      float4 loc = *(float4*)(Hp + j);
      float4 sv; sv.x = S[j]; sv.y = S[j + 1]; sv.z = S[j + 2]; sv.w = S[j + 3];
      *(float4*)(Hp + j) = sv;      // store H_in for this chunk
      S[j]     = P * S[j]     + loc.x;
      S[j + 1] = P * S[j + 1] + loc.y;
      S[j + 2] = P * S[j + 2] + loc.z;
      S[j + 3] = P * S[j + 3] + loc.w;
    }
  }
}

// ---------------- scan phase 3: y += cumdec_t * (C_t . H_in) ---------------
__global__ __launch_bounds__(256) void scan3_kernel(
    const float* __restrict__ proj, const float* __restrict__ Hbuf,
    const float* __restrict__ cumdec, float* __restrict__ ybuf) {
  int c = blockIdx.x & 15, bh = blockIdx.x >> 4;
  if (c == 0) return;                      // H_in is zero for first chunk
  int b = bh / NH, h = bh - b * NH;
  __shared__ float sH[64][65];
  __shared__ float sC[64][64];
  int t = threadIdx.x;
  int p = t >> 2, q = t & 3;
  {
    const float* Hp = Hbuf + ((size_t)(bh * NCHUNK + c)) * 4096 + p * 64 + q * 16;
    const float* Cp = proj + ((size_t)(b * SEQ + c * CLEN + p)) * PP + 4608 + h * 64 + q * 16;
#pragma unroll
    for (int k = 0; k < 16; k += 4) {
      float4 hv = *(const float4*)(Hp + k);
      sH[p][q * 16 + k] = hv.x; sH[p][q * 16 + k + 1] = hv.y;
      sH[p][q * 16 + k + 2] = hv.z; sH[p][q * 16 + k + 3] = hv.w;
      float4 cv = *(const float4*)(Cp + k);
      sC[p][q * 16 + k] = cv.x; sC[p][q * 16 + k + 1] = cv.y;
      sC[p][q * 16 + k + 2] = cv.z; sC[p][q * 16 + k + 3] = cv.w;
    }
  }
  __syncthreads();
  int m0 = b * SEQ + c * CLEN;
  for (int s = 0; s < CLEN; ++s) {
    float sum = 0.f;
#pragma unroll
    for (int k = 0; k < 16; ++k) sum += sC[s][q * 16 + k] * sH[p][q * 16 + k];
    sum += __shfl_xor(sum, 1);
    sum += __shfl_xor(sum, 2);
    if (q == 0) {
      size_t m = m0 + s;
      ybuf[m * DINNER + h * 64 + p] += cumdec[m * NH + h] * sum;
    }
  }
}

// ---------------- act: (y + skip) * silu(z) -> bf16 ------------------------
__global__ void act_kernel(const float* __restrict__ ybuf, const float* __restrict__ skip_b,
                           const float* __restrict__ proj, u16* __restrict__ act) {
  int i = blockIdx.x * 256 + threadIdx.x;   // < M*DINNER
  int m = i / DINNER;
  int ci = i - m * DINNER;
  int h = ci >> 6;
  float yv = ybuf[i] + skip_b[(size_t)m * NH + h];
  float z = proj[(size_t)m * PP + ci];
  float sg = 1.f / (1.f + expf(-z));
  act[i] = f2bf(yv * z * sg);
}

// ---------------- glu: silu(g)*u -> bf16 -----------------------------------
__global__ void glu_kernel(const float* __restrict__ g, const float* __restrict__ u,
                           u16* __restrict__ gu) {
  int i = blockIdx.x * 256 + threadIdx.x;   // < M*DMLP
  float gv = g[i], uv = u[i];
  float s = gv / (1.f + expf(-gv));
  gu[i] = f2bf(s * uv);
}

// ---------------- final: out = x2 + mlp ------------------------------------
__global__ void final_add_kernel(const float* __restrict__ x2, const float* __restrict__ mlp,
                                 float* __restrict__ out) {
  int i = blockIdx.x * 256 + threadIdx.x;   // < M*DMODEL
  out[i] = x2[i] + mlp[i];
}

extern "C" void kernel_launch(void* const* d_in, const int* in_sizes, int n_in,
                              void* d_out, int out_size, void* d_ws, size_t ws_size,
                              hipStream_t stream) {
  (void)in_sizes; (void)n_in; (void)out_size; (void)ws_size;
  const float* x      = (const float*)d_in[0];
  const float* n1w    = (const float*)d_in[1];
  const float* n2w    = (const float*)d_in[2];
  const float* w_in   = (const float*)d_in[3];
  const float* w_out  = (const float*)d_in[4];
  const float* A_log  = (const float*)d_in[5];
  const float* Dv     = (const float*)d_in[6];
  const float* dt_b   = (const float*)d_in[7];
  const float* B_bias = (const float*)d_in[8];
  const float* C_bias = (const float*)d_in[9];
  const float* Bnw    = (const float*)d_in[10];
  const float* Cnw    = (const float*)d_in[11];
  const float* w_g    = (const float*)d_in[12];
  const float* w_u    = (const float*)d_in[13];
  const float* w_d    = (const float*)d_in[14];
  float* out = (float*)d_out;

  char* ws = (char*)d_ws;
  size_t off = 0;
  auto alloc = [&](size_t bytes) -> char* {
    char* p = ws + off;
    off = (off + bytes + 255) & ~(size_t)255;
    return p;
  };
  u16*   wb_in  = (u16*)  alloc((size_t)PP * DMODEL * 2);
  u16*   wb_out = (u16*)  alloc((size_t)DMODEL * DINNER * 2);
  u16*   wb_g   = (u16*)  alloc((size_t)DMLP * DMODEL * 2);
  u16*   wb_u   = (u16*)  alloc((size_t)DMLP * DMODEL * 2);
  u16*   wb_d   = (u16*)  alloc((size_t)DMODEL * DMLP * 2);
  u16*   h1     = (u16*)  alloc((size_t)MROWS * DMODEL * 2);
  float* proj   = (float*)alloc((size_t)MROWS * PP * 4);
  float* alpha_b= (float*)alloc((size_t)MROWS * NH * 4);
  float* skip_b = (float*)alloc((size_t)MROWS * NH * 4);
  float* cumdec = (float*)alloc((size_t)MROWS * NH * 4);
  float* dtheta = (float*)alloc((size_t)MROWS * 768 * 4);
  float* ybuf   = (float*)alloc((size_t)MROWS * DINNER * 4);
  float* Hbuf   = (float*)alloc((size_t)B_N * NH * NCHUNK * 4096 * 4);
  u16*   actb   = (u16*)  alloc((size_t)MROWS * DINNER * 2);
  float* tmp1   = (float*)alloc((size_t)MROWS * DMODEL * 4);
  float* x2     = (float*)alloc((size_t)MROWS * DMODEL * 4);
  u16*   h2     = (u16*)  alloc((size_t)MROWS * DMODEL * 2);
  // g/u/gu/mlp overlay the proj region (proj dead after act+scan3)
  float* gbuf   = proj;
  float* ubuf   = gbuf + (size_t)MROWS * DMLP;
  u16*   gub    = (u16*)(ubuf + (size_t)MROWS * DMLP);
  float* mlpbuf = (float*)((char*)gub + (size_t)MROWS * DMLP * 2);

  // 1. weight casts
  {
    int tot = PP * DMODEL;
    cast_w_kernel<<<(tot + 255) / 256, 256, 0, stream>>>(w_in, wb_in, NPROJ, DMODEL, tot);
    tot = DMODEL * DINNER;
    cast_w_kernel<<<(tot + 255) / 256, 256, 0, stream>>>(w_out, wb_out, DMODEL, DINNER, tot);
    tot = DMLP * DMODEL;
    cast_w_kernel<<<(tot + 255) / 256, 256, 0, stream>>>(w_g, wb_g, DMLP, DMODEL, tot);
    cast_w_kernel<<<(tot + 255) / 256, 256, 0, stream>>>(w_u, wb_u, DMLP, DMODEL, tot);
    tot = DMODEL * DMLP;
    cast_w_kernel<<<(tot + 255) / 256, 256, 0, stream>>>(w_d, wb_d, DMODEL, DMLP, tot);
  }
  // 2. rmsnorm1 -> h1 (bf16)
  add_rmsnorm_kernel<<<MROWS, 256, 0, stream>>>(x, nullptr, n1w, nullptr, h1);
  // 3. in_proj GEMM -> proj
  {
    dim3 g(PP / 128, MROWS / 128);
    gemm_bt_kernel<<<g, 256, 0, stream>>>(h1, wb_in, proj, DMODEL, PP);
  }
  // 4. prep (B/C norms, dt, alpha, skip, dtheta, x*gamma)
  prep_kernel<<<MROWS * NH / 4, 256, 0, stream>>>(proj, A_log, Dv, dt_b, B_bias, C_bias,
                                                  Bnw, Cnw, alpha_b, skip_b, dtheta);
  // 5. cumsum over s
  cumsum_kernel<<<6, 256, 0, stream>>>(dtheta);
  // 6. rope on B/C
  rope_kernel<<<MROWS * NH / 4, 256, 0, stream>>>(proj, nullptr, dtheta);
  // 7-9. chunked scan
  scan1_kernel<<<B_N * NH * NCHUNK, 256, 0, stream>>>(proj, alpha_b, ybuf, Hbuf, cumdec);
  scan2_kernel<<<B_N * NH, 256, 0, stream>>>(Hbuf, cumdec);
  scan3_kernel<<<B_N * NH * NCHUNK, 256, 0, stream>>>(proj, Hbuf, cumdec, ybuf);
  // 10. gate with z, skip -> act bf16
  act_kernel<<<MROWS * DINNER / 256, 256, 0, stream>>>(ybuf, skip_b, proj, actb);
  // 11. out_proj GEMM -> tmp1
  {
    dim3 g(DMODEL / 128, MROWS / 128);
    gemm_bt_kernel<<<g, 256, 0, stream>>>(actb, wb_out, tmp1, DINNER, DMODEL);
  }
  // 12. x2 = x + tmp1 ; h2 = rmsnorm(x2) bf16
  add_rmsnorm_kernel<<<MROWS, 256, 0, stream>>>(x, tmp1, n2w, x2, h2);
  // 13. gate & up GEMMs (overlay proj region)
  {
    dim3 g(DMLP / 128, MROWS / 128);
    gemm_bt_kernel<<<g, 256, 0, stream>>>(h2, wb_g, gbuf, DMODEL, DMLP);
    gemm_bt_kernel<<<g, 256, 0, stream>>>(h2, wb_u, ubuf, DMODEL, DMLP);
  }
  // 14. glu
  glu_kernel<<<MROWS * DMLP / 256, 256, 0, stream>>>(gbuf, ubuf, gub);
  // 15. down GEMM
  {
    dim3 g(DMODEL / 128, MROWS / 128);
    gemm_bt_kernel<<<g, 256, 0, stream>>>(gub, wb_d, mlpbuf, DMLP, DMODEL);
  }
  // 16. final add
  final_add_kernel<<<MROWS * DMODEL / 256, 256, 0, stream>>>(x2, mlpbuf, out);
}

// Round 2
// 433.635 us; speedup vs baseline: 1.1420x; 1.1420x over previous
//
#include <hip/hip_runtime.h>

typedef unsigned short u16;
typedef __attribute__((ext_vector_type(8))) short short8;
typedef __attribute__((ext_vector_type(4))) float f32x4;

constexpr int B_N    = 2;
constexpr int SEQ    = 1024;
constexpr int DMODEL = 768;
constexpr int DINNER = 1536;
constexpr int NH     = 24;
constexpr int DMLP   = 1920;
constexpr int NPROJ  = 6936;
constexpr int PP     = 7040;          // padded proj width (55*128)
constexpr int MROWS  = B_N * SEQ;     // 2048
constexpr int NCHUNK = 16;
constexpr int CLEN   = 64;

__device__ __forceinline__ u16 f2bf(float f) {
  union { float f; unsigned u; } x; x.f = f;
  unsigned r = x.u + 0x7fffu + ((x.u >> 16) & 1u);
  return (u16)(r >> 16);
}

__device__ __forceinline__ void gld_lds16(const u16* g, u16* l) {
  __builtin_amdgcn_global_load_lds((const __attribute__((address_space(1))) void*)g,
                                   (__attribute__((address_space(3))) void*)l, 16, 0, 0);
}

// ---------------- one cast kernel for all weights (f32 -> bf16) -------------
constexpr size_t E0  = (size_t)PP * DMODEL;       // padded in_proj
constexpr size_t E0s = (size_t)NPROJ * DMODEL;    // real in_proj rows
constexpr size_t E1  = (size_t)DMODEL * DINNER;   // out_proj
constexpr size_t E2  = (size_t)DMLP * DMODEL;     // gate (= up = down size)
constexpr size_t ETOT = E0 + E1 + 3 * E2;

__global__ void cast_all_kernel(const float* __restrict__ w_in, const float* __restrict__ w_out,
                                const float* __restrict__ w_g, const float* __restrict__ w_u,
                                const float* __restrict__ w_d,
                                u16* __restrict__ wb_in, u16* __restrict__ wb_out,
                                u16* __restrict__ wb_gu, u16* __restrict__ wb_d) {
  size_t i = ((size_t)blockIdx.x * 256 + threadIdx.x) * 4;
  if (i >= ETOT) return;
  float4 v; u16* dst;
  if (i < E0) {
    dst = wb_in + i;
    if (i < E0s) v = *(const float4*)(w_in + i);
    else { v.x = v.y = v.z = v.w = 0.f; }
  } else if (i < E0 + E1) {
    size_t k = i - E0; dst = wb_out + k; v = *(const float4*)(w_out + k);
  } else if (i < E0 + E1 + E2) {
    size_t k = i - E0 - E1; dst = wb_gu + k; v = *(const float4*)(w_g + k);
  } else if (i < E0 + E1 + 2 * E2) {
    size_t k = i - E0 - E1 - E2; dst = wb_gu + E2 + k; v = *(const float4*)(w_u + k);
  } else {
    size_t k = i - E0 - E1 - 2 * E2; dst = wb_d + k; v = *(const float4*)(w_d + k);
  }
  short4 o;
  o.x = (short)f2bf(v.x); o.y = (short)f2bf(v.y);
  o.z = (short)f2bf(v.z); o.w = (short)f2bf(v.w);
  *(short4*)dst = o;
}

// ---------------- fused (a [+ b]) -> rmsnorm -> bf16 ; optional raw-sum out --
__global__ __launch_bounds__(256) void add_rmsnorm_kernel(
    const float* __restrict__ a, const float* __restrict__ b,
    const float* __restrict__ w, float* __restrict__ sum_out,
    u16* __restrict__ hout) {
  int row = blockIdx.x;
  int t = threadIdx.x;
  const float* pa = a + (size_t)row * DMODEL;
  const float* pb = b ? b + (size_t)row * DMODEL : nullptr;
  float v[3]; float ss = 0.f;
#pragma unroll
  for (int i = 0; i < 3; ++i) {
    int c = t + i * 256;
    float x = pa[c];
    if (pb) x += pb[c];
    v[i] = x; ss += x * x;
  }
#pragma unroll
  for (int o = 32; o > 0; o >>= 1) ss += __shfl_xor(ss, o);
  __shared__ float red[4];
  if ((t & 63) == 0) red[t >> 6] = ss;
  __syncthreads();
  ss = red[0] + red[1] + red[2] + red[3];
  float sc = rsqrtf(ss * (1.f / DMODEL) + 1e-5f);
#pragma unroll
  for (int i = 0; i < 3; ++i) {
    int c = t + i * 256;
    if (sum_out) sum_out[(size_t)row * DMODEL + c] = v[i];
    hout[(size_t)row * DMODEL + c] = f2bf(v[i] * sc * w[c]);
  }
}

// ---------------- bf16 MFMA GEMM: C(M x N, f32, ldc) = A(MxK) * B(NxK)^T ----
// grid = (N/128, M/BM), block = 256 (4 waves, 2x2). XCD-chunked column-major
// swizzle (requires nwg % 8 == 0 -- true for all our launches).
template<int BM>
__global__ __launch_bounds__(256) void gemm_bt_kernel(
    const u16* __restrict__ A, const u16* __restrict__ Bw,
    float* __restrict__ C, int K, int ldc) {
  constexpr int MI = BM / 32;           // 16-row fragments per wave
  __shared__ u16 As[BM * 64];
  __shared__ u16 Bs[128 * 64];
  const int t = threadIdx.x;
  const int lane = t & 63;
  const int wave = t >> 6;
  const int wm = wave >> 1, wn = wave & 1;
  const int gx = gridDim.x, gy = gridDim.y;
  const int o = blockIdx.y * gx + blockIdx.x;
  const int nwg = gx * gy;
  const int cid = (o & 7) * (nwg >> 3) + (o >> 3);   // chunk per XCD
  const int bx = cid / gy, by = cid - bx * gy;       // column-major decompose
  const int m0 = by * BM, n0 = bx * 128;
  f32x4 acc[MI][4] = {};
  const int rr = t >> 3;          // 0..31  (row within 32-row slab)
  const int kc = (t & 7) * 8;     // 0..56  (k element offset)
  const u16* ga = A + (size_t)(m0 + rr) * K + kc;
  const u16* gb = Bw + (size_t)(n0 + rr) * K + kc;
  for (int kt = 0; kt < K; kt += 64) {
    __syncthreads();
#pragma unroll
    for (int i = 0; i < MI; ++i)
      gld_lds16(ga + (size_t)i * 32 * K + kt, As + i * 2048 + t * 8);
#pragma unroll
    for (int i = 0; i < 4; ++i)
      gld_lds16(gb + (size_t)i * 32 * K + kt, Bs + i * 2048 + t * 8);
    __syncthreads();
#pragma unroll
    for (int kh = 0; kh < 2; ++kh) {
      short8 af[MI], bfr[4];
#pragma unroll
      for (int i = 0; i < MI; ++i)
        af[i] = *(const short8*)(As + (wm * (BM / 2) + i * 16 + (lane & 15)) * 64 + kh * 32 + (lane >> 4) * 8);
#pragma unroll
      for (int j = 0; j < 4; ++j)
        bfr[j] = *(const short8*)(Bs + (wn * 64 + j * 16 + (lane & 15)) * 64 + kh * 32 + (lane >> 4) * 8);
#pragma unroll
      for (int i = 0; i < MI; ++i)
#pragma unroll
        for (int j = 0; j < 4; ++j)
          acc[i][j] = __builtin_amdgcn_mfma_f32_16x16x32_bf16(af[i], bfr[j], acc[i][j], 0, 0, 0);
    }
  }
  const int cr = (lane >> 4) * 4;
  const int cc = lane & 15;
#pragma unroll
  for (int i = 0; i < MI; ++i) {
#pragma unroll
    for (int j = 0; j < 4; ++j) {
      int row = m0 + wm * (BM / 2) + i * 16 + cr;
      int col = n0 + wn * 64 + j * 16 + cc;
      float* cp = C + (size_t)row * ldc + col;
#pragma unroll
      for (int r = 0; r < 4; ++r) cp[(size_t)r * ldc] = acc[i][j][r];
    }
  }
}

// ---------------- prep: B/C rmsnorm+bias (in place), dt/alpha, skip, dtheta,
//                  pre-scale x_ssm by gamma. One wave per (m,h). ------------
__global__ __launch_bounds__(256) void prep_kernel(
    float* __restrict__ proj, const float* __restrict__ A_log,
    const float* __restrict__ Dv, const float* __restrict__ dt_bias,
    const float* __restrict__ B_bias, const float* __restrict__ C_bias,
    const float* __restrict__ Bnw, const float* __restrict__ Cnw,
    float* __restrict__ alpha_b, float* __restrict__ skip_b,
    float* __restrict__ dtheta) {
  int wid = blockIdx.x * 4 + (threadIdx.x >> 6);
  int lane = threadIdx.x & 63;
  int m = wid / NH, h = wid - m * NH;
  float* row = proj + (size_t)m * PP;

  float Braw = row[3072 + h * 64 + lane];
  float Craw = row[4608 + h * 64 + lane];
  float sb = Braw * Braw, sc2 = Craw * Craw;
#pragma unroll
  for (int o = 32; o > 0; o >>= 1) { sb += __shfl_xor(sb, o); sc2 += __shfl_xor(sc2, o); }
  float rb = rsqrtf(sb * (1.f / 64.f) + 1e-5f);
  float rc = rsqrtf(sc2 * (1.f / 64.f) + 1e-5f);
  row[3072 + h * 64 + lane] = Braw * rb * Bnw[lane] + B_bias[h * 64 + lane];
  row[4608 + h * 64 + lane] = Craw * rc * Cnw[lane] + C_bias[h * 64 + lane];

  float dtr = row[6144 + h] + dt_bias[h];
  float dt = dtr > 20.f ? dtr : log1pf(expf(dtr));
  float A = -expf(A_log[h]) * dt;
  float alpha = expf(A);
  float gamma = (alpha - 1.f) / (A + 1e-6f) * 0.5f + 1.f;

  float xv = row[1536 + h * 64 + lane];
  float sx = xv;
#pragma unroll
  for (int o = 32; o > 0; o >>= 1) sx += __shfl_xor(sx, o);
  row[1536 + h * 64 + lane] = xv * gamma;   // pre-scale for scan

  if (lane == 0) {
    alpha_b[(size_t)m * NH + h] = alpha;
    skip_b[(size_t)m * NH + h] = Dv[h] * sx;
  }
  if (lane < 32) {
    float th = row[6168 + h * 32 + lane];
    dtheta[(size_t)m * 768 + h * 32 + lane] = dt * th;
  }
}

// ---------------- chunked cumsum of dtheta over s ---------------------------
// phase A: in-place chunk-local inclusive cumsum + chunk totals
__global__ __launch_bounds__(256) void cumsum_a_kernel(float* __restrict__ dtheta,
                                                       float* __restrict__ ctot) {
  int bid = blockIdx.x;                  // 96 = 2 * 16 * 3
  int cb = bid % 3, rest = bid / 3;
  int c = rest & 15, b = rest >> 4;
  int col = cb * 256 + threadIdx.x;
  float* p = dtheta + ((size_t)(b * SEQ + c * CLEN)) * 768 + col;
  float acc = 0.f;
#pragma unroll 4
  for (int s = 0; s < CLEN; ++s) {
    acc += p[(size_t)s * 768];
    p[(size_t)s * 768] = acc;
  }
  ctot[((size_t)b * NCHUNK + c) * 768 + col] = acc;
}

// phase B: exclusive prefix over the 16 chunk totals (in place)
__global__ void cumsum_b_kernel(float* __restrict__ ctot) {
  int tid = blockIdx.x * 256 + threadIdx.x;   // < 1536
  int b = tid / 768, col = tid - b * 768;
  float pre = 0.f;
#pragma unroll
  for (int c = 0; c < NCHUNK; ++c) {
    size_t o = ((size_t)b * NCHUNK + c) * 768 + col;
    float v = ctot[o];
    ctot[o] = pre;
    pre += v;
  }
}

// ---------------- RoPE on B (lanes 0..31) and C (lanes 32..63), in place ----
__global__ __launch_bounds__(256) void rope_kernel(
    float* __restrict__ proj, const float* __restrict__ dloc,
    const float* __restrict__ ctot) {
  int wid = blockIdx.x * 4 + (threadIdx.x >> 6);
  int lane = threadIdx.x & 63;
  int m = wid / NH, h = wid - m * NH;
  int j = lane & 31;
  int b = m >> 10;            // m / SEQ
  int c = (m >> 6) & 15;      // chunk
  float ang = dloc[(size_t)m * 768 + h * 32 + j] +
              ctot[((size_t)b * NCHUNK + c) * 768 + h * 32 + j];
  float sn, cs;
  sincosf(ang, &sn, &cs);
  int base = (lane < 32) ? 3072 : 4608;
  float2* p = (float2*)(proj + (size_t)m * PP + base + h * 64) + j;
  float2 v = *p;
  float2 o; o.x = cs * v.x - sn * v.y; o.y = sn * v.x + cs * v.y;
  *p = o;
}

// ---------------- scan phase 1: intra-chunk scan from zero state -----------
// block = (bh, chunk); bulk LDS staging, fully unrolled recurrence.
__global__ __launch_bounds__(256) void scan1_kernel(
    const float* __restrict__ proj, const float* __restrict__ alpha_b,
    float* __restrict__ ybuf, float* __restrict__ Hbuf,
    float* __restrict__ cumdec) {
  int c = blockIdx.x & 15, bh = blockIdx.x >> 4;
  int b = bh / NH, h = bh - b * NH;
  int t = threadIdx.x, w = t >> 6, l = t & 63;
  __shared__ float sB[64][64], sC[64][64], sX[64][64];
  __shared__ float sAl[64];
  int m0 = b * SEQ + c * CLEN;
  {
    int s = t >> 2, q = t & 3;
    const float* row = proj + (size_t)(m0 + s) * PP + h * 64;
#pragma unroll
    for (int k = 0; k < 4; ++k) {
      int e = q * 16 + k * 4;
      *(float4*)&sB[s][e] = *(const float4*)&row[3072 + e];
      *(float4*)&sC[s][e] = *(const float4*)&row[4608 + e];
      *(float4*)&sX[s][e] = *(const float4*)&row[1536 + e];
    }
    if (t < 64) sAl[t] = alpha_b[(size_t)(m0 + t) * NH + h];
  }
  __syncthreads();
  // cumdec: wave 0 does a 64-lane inclusive prefix product of alpha
  if (w == 0) {
    float v = sAl[l];
#pragma unroll
    for (int o = 1; o < 64; o <<= 1) {
      float u = __shfl_up(v, o);
      if (l >= o) v *= u;
    }
    cumdec[(size_t)(m0 + l) * NH + h] = v;
  }
  // recurrence: wave w owns n in [w*16, w*16+16), lane = p
  float hst[16];
#pragma unroll
  for (int j = 0; j < 16; ++j) hst[j] = 0.f;
  float ps[64];
#pragma unroll
  for (int s = 0; s < CLEN; ++s) {
    float a = sAl[s];
    float xp = sX[s][l];
    float acc = 0.f;
#pragma unroll
    for (int j = 0; j < 16; ++j) {
      hst[j] = hst[j] * a + sB[s][w * 16 + j] * xp;
      acc += hst[j] * sC[s][w * 16 + j];
    }
    ps[s] = acc;
  }
  // cross-wave reduce into sX (dead after the loop)
  __syncthreads();
  if (w == 0) {
#pragma unroll
    for (int s = 0; s < CLEN; ++s) sX[s][l] = ps[s];
  }
  __syncthreads();
  if (w != 0) {
#pragma unroll
    for (int s = 0; s < CLEN; ++s) atomicAdd(&sX[s][l], ps[s]);
  }
  __syncthreads();
#pragma unroll
  for (int r = 0; r < 16; ++r) {
    int i = r * 256 + t;
    int s = i >> 6, p = i & 63;
    ybuf[(size_t)(m0 + s) * DINNER + h * 64 + p] = sX[s][p];
  }
  float* Hp = Hbuf + ((size_t)(bh * NCHUNK + c)) * 4096 + l * 64 + w * 16;
#pragma unroll
  for (int j = 0; j < 16; j += 4) {
    float4 v; v.x = hst[j]; v.y = hst[j + 1]; v.z = hst[j + 2]; v.w = hst[j + 3];
    *(float4*)(Hp + j) = v;
  }
}

// ---------------- scan phase 2: chunk-level recurrence; Hbuf becomes H_in ---
__global__ __launch_bounds__(256) void scan2_kernel(
    float* __restrict__ Hbuf, const float* __restrict__ cumdec) {
  int bh = blockIdx.x;
  int b = bh / NH, h = bh - b * NH;
  int e = threadIdx.x * 16;
  float S[16];
#pragma unroll
  for (int j = 0; j < 16; ++j) S[j] = 0.f;
  for (int c = 0; c < NCHUNK; ++c) {
    float* Hp = Hbuf + ((size_t)(bh * NCHUNK + c)) * 4096 + e;
    float P = cumdec[(size_t)(b * SEQ + c * CLEN + CLEN - 1) * NH + h];
#pragma unroll
    for (int j = 0; j < 16; j += 4) {
      float4 loc = *(float4*)(Hp + j);
      float4 sv; sv.x = S[j]; sv.y = S[j + 1]; sv.z = S[j + 2]; sv.w = S[j + 3];
      *(float4*)(Hp + j) = sv;      // store H_in for this chunk
      S[j]     = P * S[j]     + loc.x;
      S[j + 1] = P * S[j + 1] + loc.y;
      S[j + 2] = P * S[j + 2] + loc.z;
      S[j + 3] = P * S[j + 3] + loc.w;
    }
  }
}

// ---------------- scan phase 3: y += cumdec_t * (C_t . H_in) ---------------
__global__ __launch_bounds__(256) void scan3_kernel(
    const float* __restrict__ proj, const float* __restrict__ Hbuf,
    const float* __restrict__ cumdec, float* __restrict__ ybuf) {
  int c = blockIdx.x & 15, bh = blockIdx.x >> 4;
  if (c == 0) return;                      // H_in is zero for first chunk
  int b = bh / NH, h = bh - b * NH;
  __shared__ float sH[64][65];
  __shared__ float sC[64][64];
  int t = threadIdx.x;
  int p = t >> 2, q = t & 3;
  {
    const float* Hp = Hbuf + ((size_t)(bh * NCHUNK + c)) * 4096 + p * 64 + q * 16;
    const float* Cp = proj + ((size_t)(b * SEQ + c * CLEN + p)) * PP + 4608 + h * 64 + q * 16;
#pragma unroll
    for (int k = 0; k < 16; k += 4) {
      float4 hv = *(const float4*)(Hp + k);
      sH[p][q * 16 + k] = hv.x; sH[p][q * 16 + k + 1] = hv.y;
      sH[p][q * 16 + k + 2] = hv.z; sH[p][q * 16 + k + 3] = hv.w;
      float4 cv = *(const float4*)(Cp + k);
      sC[p][q * 16 + k] = cv.x; sC[p][q * 16 + k + 1] = cv.y;
      sC[p][q * 16 + k + 2] = cv.z; sC[p][q * 16 + k + 3] = cv.w;
    }
  }
  __syncthreads();
  int m0 = b * SEQ + c * CLEN;
  for (int s = 0; s < CLEN; ++s) {
    float sum = 0.f;
#pragma unroll
    for (int k = 0; k < 16; ++k) sum += sC[s][q * 16 + k] * sH[p][q * 16 + k];
    sum += __shfl_xor(sum, 1);
    sum += __shfl_xor(sum, 2);
    if (q == 0) {
      size_t m = m0 + s;
      ybuf[m * DINNER + h * 64 + p] += cumdec[m * NH + h] * sum;
    }
  }
}

// ---------------- act: (y + skip) * silu(z) -> bf16 ------------------------
__global__ void act_kernel(const float* __restrict__ ybuf, const float* __restrict__ skip_b,
                           const float* __restrict__ proj, u16* __restrict__ act) {
  int i = blockIdx.x * 256 + threadIdx.x;   // < M*DINNER
  int m = i / DINNER;
  int ci = i - m * DINNER;
  int h = ci >> 6;
  float yv = ybuf[i] + skip_b[(size_t)m * NH + h];
  float z = proj[(size_t)m * PP + ci];
  float sg = 1.f / (1.f + expf(-z));
  act[i] = f2bf(yv * z * sg);
}

// ---------------- glu: silu(g)*u -> bf16 (g,u stacked in one buffer) --------
__global__ void glu_kernel(const float* __restrict__ gu_all, u16* __restrict__ gub) {
  int i = blockIdx.x * 256 + threadIdx.x;   // < M*DMLP
  int m = i / DMLP;
  int ci = i - m * DMLP;
  float gv = gu_all[(size_t)m * 2 * DMLP + ci];
  float uv = gu_all[(size_t)m * 2 * DMLP + DMLP + ci];
  float s = gv / (1.f + expf(-gv));
  gub[i] = f2bf(s * uv);
}

// ---------------- final: out = x2 + mlp ------------------------------------
__global__ void final_add_kernel(const float* __restrict__ x2, const float* __restrict__ mlp,
                                 float* __restrict__ out) {
  int i = blockIdx.x * 256 + threadIdx.x;   // < M*DMODEL
  out[i] = x2[i] + mlp[i];
}

extern "C" void kernel_launch(void* const* d_in, const int* in_sizes, int n_in,
                              void* d_out, int out_size, void* d_ws, size_t ws_size,
                              hipStream_t stream) {
  (void)in_sizes; (void)n_in; (void)out_size; (void)ws_size;
  const float* x      = (const float*)d_in[0];
  const float* n1w    = (const float*)d_in[1];
  const float* n2w    = (const float*)d_in[2];
  const float* w_in   = (const float*)d_in[3];
  const float* w_out  = (const float*)d_in[4];
  const float* A_log  = (const float*)d_in[5];
  const float* Dv     = (const float*)d_in[6];
  const float* dt_b   = (const float*)d_in[7];
  const float* B_bias = (const float*)d_in[8];
  const float* C_bias = (const float*)d_in[9];
  const float* Bnw    = (const float*)d_in[10];
  const float* Cnw    = (const float*)d_in[11];
  const float* w_g    = (const float*)d_in[12];
  const float* w_u    = (const float*)d_in[13];
  const float* w_d    = (const float*)d_in[14];
  float* out = (float*)d_out;

  char* ws = (char*)d_ws;
  size_t off = 0;
  auto alloc = [&](size_t bytes) -> char* {
    char* p = ws + off;
    off = (off + bytes + 255) & ~(size_t)255;
    return p;
  };
  u16*   wb_in  = (u16*)  alloc(E0 * 2);
  u16*   wb_out = (u16*)  alloc(E1 * 2);
  u16*   wb_gu  = (u16*)  alloc(E2 * 2 * 2);            // gate rows then up rows
  u16*   wb_d   = (u16*)  alloc(E2 * 2);
  u16*   h1     = (u16*)  alloc((size_t)MROWS * DMODEL * 2);
  float* proj   = (float*)alloc((size_t)MROWS * PP * 4);
  float* alpha_b= (float*)alloc((size_t)MROWS * NH * 4);
  float* skip_b = (float*)alloc((size_t)MROWS * NH * 4);
  float* cumdec = (float*)alloc((size_t)MROWS * NH * 4);
  float* dtheta = (float*)alloc((size_t)MROWS * 768 * 4);
  float* ctot   = (float*)alloc((size_t)B_N * NCHUNK * 768 * 4);
  float* ybuf   = (float*)alloc((size_t)MROWS * DINNER * 4);
  float* Hbuf   = (float*)alloc((size_t)B_N * NH * NCHUNK * 4096 * 4);
  u16*   actb   = (u16*)  alloc((size_t)MROWS * DINNER * 2);
  float* tmp1   = (float*)alloc((size_t)MROWS * DMODEL * 4);
  float* x2     = (float*)alloc((size_t)MROWS * DMODEL * 4);
  u16*   h2     = (u16*)  alloc((size_t)MROWS * DMODEL * 2);
  // MLP buffers overlay proj (dead after act): [M][3840] f32 + [M][1920] bf16 + [M][768] f32
  float* gu_all = proj;
  u16*   gub    = (u16*)(proj + (size_t)MROWS * 2 * DMLP);
  float* mlpbuf = (float*)((char*)gub + (size_t)MROWS * DMLP * 2 + 256);

  // 1. all weight casts in one kernel
  cast_all_kernel<<<(int)((ETOT / 4 + 255) / 256), 256, 0, stream>>>(
      w_in, w_out, w_g, w_u, w_d, wb_in, wb_out, wb_gu, wb_d);
  // 2. rmsnorm1 -> h1 (bf16)
  add_rmsnorm_kernel<<<MROWS, 256, 0, stream>>>(x, nullptr, n1w, nullptr, h1);
  // 3. in_proj GEMM -> proj (55x16 = 880 blocks)
  {
    dim3 g(PP / 128, MROWS / 128);
    gemm_bt_kernel<128><<<g, 256, 0, stream>>>(h1, wb_in, proj, DMODEL, PP);
  }
  // 4. prep
  prep_kernel<<<MROWS * NH / 4, 256, 0, stream>>>(proj, A_log, Dv, dt_b, B_bias, C_bias,
                                                  Bnw, Cnw, alpha_b, skip_b, dtheta);
  // 5. chunked cumsum
  cumsum_a_kernel<<<B_N * NCHUNK * 3, 256, 0, stream>>>(dtheta, ctot);
  cumsum_b_kernel<<<6, 256, 0, stream>>>(ctot);
  // 6. rope
  rope_kernel<<<MROWS * NH / 4, 256, 0, stream>>>(proj, dtheta, ctot);
  // 7-9. chunked scan
  scan1_kernel<<<B_N * NH * NCHUNK, 256, 0, stream>>>(proj, alpha_b, ybuf, Hbuf, cumdec);
  scan2_kernel<<<B_N * NH, 256, 0, stream>>>(Hbuf, cumdec);
  scan3_kernel<<<B_N * NH * NCHUNK, 256, 0, stream>>>(proj, Hbuf, cumdec, ybuf);
  // 10. gate with z, skip -> act bf16
  act_kernel<<<MROWS * DINNER / 256, 256, 0, stream>>>(ybuf, skip_b, proj, actb);
  // 11. out_proj GEMM -> tmp1 (6x32 = 192 blocks)
  {
    dim3 g(DMODEL / 128, MROWS / 64);
    gemm_bt_kernel<64><<<g, 256, 0, stream>>>(actb, wb_out, tmp1, DINNER, DMODEL);
  }
  // 12. x2 = x + tmp1 ; h2 = rmsnorm(x2) bf16
  add_rmsnorm_kernel<<<MROWS, 256, 0, stream>>>(x, tmp1, n2w, x2, h2);
  // 13. stacked gate+up GEMM (30x16 = 480 blocks) -> gu_all
  {
    dim3 g(2 * DMLP / 128, MROWS / 128);
    gemm_bt_kernel<128><<<g, 256, 0, stream>>>(h2, wb_gu, gu_all, DMODEL, 2 * DMLP);
  }
  // 14. glu
  glu_kernel<<<MROWS * DMLP / 256, 256, 0, stream>>>(gu_all, gub);
  // 15. down GEMM (6x32 = 192 blocks)
  {
    dim3 g(DMODEL / 128, MROWS / 64);
    gemm_bt_kernel<64><<<g, 256, 0, stream>>>(gub, wb_d, mlpbuf, DMLP, DMODEL);
  }
  // 16. final add
  final_add_kernel<<<MROWS * DMODEL / 256, 256, 0, stream>>>(x2, mlpbuf, out);
}

// Round 3
// 341.249 us; speedup vs baseline: 1.4511x; 1.2707x over previous
//
#include <hip/hip_runtime.h>

typedef unsigned short u16;
typedef __attribute__((ext_vector_type(8))) short short8;
typedef __attribute__((ext_vector_type(4))) float f32x4;

constexpr int B_N    = 2;
constexpr int SEQ    = 1024;
constexpr int DMODEL = 768;
constexpr int DINNER = 1536;
constexpr int NH     = 24;
constexpr int DMLP   = 1920;
constexpr int NPROJ  = 6936;
constexpr int PP     = 7040;          // padded proj width (55*128)
constexpr int MROWS  = B_N * SEQ;     // 2048
constexpr int NCHUNK = 16;
constexpr int CLEN   = 64;

__device__ __forceinline__ u16 f2bf(float f) {
  union { float f; unsigned u; } x; x.f = f;
  unsigned r = x.u + 0x7fffu + ((x.u >> 16) & 1u);
  return (u16)(r >> 16);
}

__device__ __forceinline__ void gld_lds16(const u16* g, u16* l) {
  __builtin_amdgcn_global_load_lds((const __attribute__((address_space(1))) void*)g,
                                   (__attribute__((address_space(3))) void*)l, 16, 0, 0);
}

// swizzled bf16 fragment read: 8 consecutive (swizzled) elements at (row, colblock cb)
__device__ __forceinline__ short8 frag(const u16* base, int row, int cb) {
  return *(const short8*)(base + row * 64 + ((cb ^ (row & 7)) << 3));
}
__device__ __forceinline__ int swz_idx(int row, int e) {   // e multiple-of-4-safe element idx
  return (((e >> 3) ^ (row & 7)) << 3) | (e & 7);
}

// ---------------- one cast kernel for all weights (f32 -> bf16) -------------
constexpr size_t E0  = (size_t)PP * DMODEL;
constexpr size_t E0s = (size_t)NPROJ * DMODEL;
constexpr size_t E1  = (size_t)DMODEL * DINNER;
constexpr size_t E2  = (size_t)DMLP * DMODEL;
constexpr size_t ETOT = E0 + E1 + 3 * E2;

__global__ void cast_all_kernel(const float* __restrict__ w_in, const float* __restrict__ w_out,
                                const float* __restrict__ w_g, const float* __restrict__ w_u,
                                const float* __restrict__ w_d,
                                u16* __restrict__ wb_in, u16* __restrict__ wb_out,
                                u16* __restrict__ wb_gu, u16* __restrict__ wb_d) {
  size_t i = ((size_t)blockIdx.x * 256 + threadIdx.x) * 4;
  if (i >= ETOT) return;
  float4 v; u16* dst;
  if (i < E0) {
    dst = wb_in + i;
    if (i < E0s) v = *(const float4*)(w_in + i);
    else { v.x = v.y = v.z = v.w = 0.f; }
  } else if (i < E0 + E1) {
    size_t k = i - E0; dst = wb_out + k; v = *(const float4*)(w_out + k);
  } else if (i < E0 + E1 + E2) {
    size_t k = i - E0 - E1; dst = wb_gu + k; v = *(const float4*)(w_g + k);
  } else if (i < E0 + E1 + 2 * E2) {
    size_t k = i - E0 - E1 - E2; dst = wb_gu + E2 + k; v = *(const float4*)(w_u + k);
  } else {
    size_t k = i - E0 - E1 - 2 * E2; dst = wb_d + k; v = *(const float4*)(w_d + k);
  }
  short4 o;
  o.x = (short)f2bf(v.x); o.y = (short)f2bf(v.y);
  o.z = (short)f2bf(v.z); o.w = (short)f2bf(v.w);
  *(short4*)dst = o;
}

// ---------------- fused (a [+ b]) -> rmsnorm -> bf16 ; optional raw-sum out --
__global__ __launch_bounds__(256) void add_rmsnorm_kernel(
    const float* __restrict__ a, const float* __restrict__ b,
    const float* __restrict__ w, float* __restrict__ sum_out,
    u16* __restrict__ hout) {
  int row = blockIdx.x;
  int t = threadIdx.x;
  const float* pa = a + (size_t)row * DMODEL;
  const float* pb = b ? b + (size_t)row * DMODEL : nullptr;
  float v[3]; float ss = 0.f;
#pragma unroll
  for (int i = 0; i < 3; ++i) {
    int c = t + i * 256;
    float x = pa[c];
    if (pb) x += pb[c];
    v[i] = x; ss += x * x;
  }
#pragma unroll
  for (int o = 32; o > 0; o >>= 1) ss += __shfl_xor(ss, o);
  __shared__ float red[4];
  if ((t & 63) == 0) red[t >> 6] = ss;
  __syncthreads();
  ss = red[0] + red[1] + red[2] + red[3];
  float sc = rsqrtf(ss * (1.f / DMODEL) + 1e-5f);
#pragma unroll
  for (int i = 0; i < 3; ++i) {
    int c = t + i * 256;
    if (sum_out) sum_out[(size_t)row * DMODEL + c] = v[i];
    hout[(size_t)row * DMODEL + c] = f2bf(v[i] * sc * w[c]);
  }
}

// ---------------- bf16 MFMA GEMM: C = A * B^T (+ optional addsrc) ----------
template<int BM>
__global__ __launch_bounds__(256) void gemm_bt_kernel(
    const u16* __restrict__ A, const u16* __restrict__ Bw,
    float* __restrict__ C, int K, int ldc, const float* __restrict__ addsrc) {
  constexpr int MI = BM / 32;
  __shared__ u16 As[BM * 64];
  __shared__ u16 Bs[128 * 64];
  const int t = threadIdx.x;
  const int lane = t & 63;
  const int wave = t >> 6;
  const int wm = wave >> 1, wn = wave & 1;
  const int gx = gridDim.x, gy = gridDim.y;
  const int o = blockIdx.y * gx + blockIdx.x;
  const int nwg = gx * gy;
  const int cid = (o & 7) * (nwg >> 3) + (o >> 3);
  const int bx = cid / gy, by = cid - bx * gy;
  const int m0 = by * BM, n0 = bx * 128;
  f32x4 acc[MI][4] = {};
  const int rr = t >> 3;
  const int kc = (t & 7) * 8;
  const u16* ga = A + (size_t)(m0 + rr) * K + kc;
  const u16* gb = Bw + (size_t)(n0 + rr) * K + kc;
  for (int kt = 0; kt < K; kt += 64) {
    __syncthreads();
#pragma unroll
    for (int i = 0; i < MI; ++i)
      gld_lds16(ga + (size_t)i * 32 * K + kt, As + i * 2048 + t * 8);
#pragma unroll
    for (int i = 0; i < 4; ++i)
      gld_lds16(gb + (size_t)i * 32 * K + kt, Bs + i * 2048 + t * 8);
    __syncthreads();
#pragma unroll
    for (int kh = 0; kh < 2; ++kh) {
      short8 af[MI], bfr[4];
#pragma unroll
      for (int i = 0; i < MI; ++i)
        af[i] = *(const short8*)(As + (wm * (BM / 2) + i * 16 + (lane & 15)) * 64 + kh * 32 + (lane >> 4) * 8);
#pragma unroll
      for (int j = 0; j < 4; ++j)
        bfr[j] = *(const short8*)(Bs + (wn * 64 + j * 16 + (lane & 15)) * 64 + kh * 32 + (lane >> 4) * 8);
#pragma unroll
      for (int i = 0; i < MI; ++i)
#pragma unroll
        for (int j = 0; j < 4; ++j)
          acc[i][j] = __builtin_amdgcn_mfma_f32_16x16x32_bf16(af[i], bfr[j], acc[i][j], 0, 0, 0);
    }
  }
  const int cr = (lane >> 4) * 4;
  const int cc = lane & 15;
#pragma unroll
  for (int i = 0; i < MI; ++i) {
#pragma unroll
    for (int j = 0; j < 4; ++j) {
      int row = m0 + wm * (BM / 2) + i * 16 + cr;
      int col = n0 + wn * 64 + j * 16 + cc;
      float* cp = C + (size_t)row * ldc + col;
      if (addsrc) {
        const float* ap = addsrc + (size_t)row * ldc + col;
#pragma unroll
        for (int r = 0; r < 4; ++r) cp[(size_t)r * ldc] = acc[i][j][r] + ap[(size_t)r * ldc];
      } else {
#pragma unroll
        for (int r = 0; r < 4; ++r) cp[(size_t)r * ldc] = acc[i][j][r];
      }
    }
  }
}

// ---------------- prep: B/C rmsnorm+bias (in place), A=log(alpha), skip,
//                  dtheta, pre-scale x_ssm by gamma. One wave per (m,h). ----
__global__ __launch_bounds__(256) void prep_kernel(
    float* __restrict__ proj, const float* __restrict__ A_log,
    const float* __restrict__ Dv, const float* __restrict__ dt_bias,
    const float* __restrict__ B_bias, const float* __restrict__ C_bias,
    const float* __restrict__ Bnw, const float* __restrict__ Cnw,
    float* __restrict__ Abuf, float* __restrict__ skip_b,
    float* __restrict__ dtheta) {
  int wid = blockIdx.x * 4 + (threadIdx.x >> 6);
  int lane = threadIdx.x & 63;
  int m = wid / NH, h = wid - m * NH;
  float* row = proj + (size_t)m * PP;

  float Braw = row[3072 + h * 64 + lane];
  float Craw = row[4608 + h * 64 + lane];
  float sb = Braw * Braw, sc2 = Craw * Craw;
#pragma unroll
  for (int o = 32; o > 0; o >>= 1) { sb += __shfl_xor(sb, o); sc2 += __shfl_xor(sc2, o); }
  float rb = rsqrtf(sb * (1.f / 64.f) + 1e-5f);
  float rc = rsqrtf(sc2 * (1.f / 64.f) + 1e-5f);
  row[3072 + h * 64 + lane] = Braw * rb * Bnw[lane] + B_bias[h * 64 + lane];
  row[4608 + h * 64 + lane] = Craw * rc * Cnw[lane] + C_bias[h * 64 + lane];

  float dtr = row[6144 + h] + dt_bias[h];
  float dt = dtr > 20.f ? dtr : log1pf(expf(dtr));
  float A = -expf(A_log[h]) * dt;
  float alpha = expf(A);
  float gamma = (alpha - 1.f) / (A + 1e-6f) * 0.5f + 1.f;

  float xv = row[1536 + h * 64 + lane];
  float sx = xv;
#pragma unroll
  for (int o = 32; o > 0; o >>= 1) sx += __shfl_xor(sx, o);
  row[1536 + h * 64 + lane] = xv * gamma;   // pre-scale for scan

  if (lane == 0) {
    Abuf[(size_t)m * NH + h] = A;           // log(alpha)
    skip_b[(size_t)m * NH + h] = Dv[h] * sx;
  }
  if (lane < 32) {
    float th = row[6168 + h * 32 + lane];
    dtheta[(size_t)m * 768 + h * 32 + lane] = dt * th;
  }
}

// ---------------- chunked cumsum of dtheta over s ---------------------------
__global__ __launch_bounds__(256) void cumsum_a_kernel(float* __restrict__ dtheta,
                                                       float* __restrict__ ctot) {
  int bid = blockIdx.x;                  // 96 = 2 * 16 * 3
  int cb = bid % 3, rest = bid / 3;
  int c = rest & 15, b = rest >> 4;
  int col = cb * 256 + threadIdx.x;
  float* p = dtheta + ((size_t)(b * SEQ + c * CLEN)) * 768 + col;
  float acc = 0.f;
#pragma unroll 4
  for (int s = 0; s < CLEN; ++s) {
    acc += p[(size_t)s * 768];
    p[(size_t)s * 768] = acc;
  }
  ctot[((size_t)b * NCHUNK + c) * 768 + col] = acc;
}

__global__ void cumsum_b_kernel(float* __restrict__ ctot) {
  int tid = blockIdx.x * 256 + threadIdx.x;   // < 1536
  int b = tid / 768, col = tid - b * 768;
  float pre = 0.f;
#pragma unroll
  for (int c = 0; c < NCHUNK; ++c) {
    size_t o = ((size_t)b * NCHUNK + c) * 768 + col;
    float v = ctot[o];
    ctot[o] = pre;
    pre += v;
  }
}

// ---------------- kernel A: H_out[p][n] = sum_t ratio[t] * xs[t,p] * B[t,n] --
// (rope applied to B on the fly; L = prefix-sum of A written to Lbuf)
__global__ __launch_bounds__(256) void houtA_kernel(
    const float* __restrict__ proj, const float* __restrict__ Abuf,
    const float* __restrict__ dtheta, const float* __restrict__ ctot,
    float* __restrict__ Lbuf, float* __restrict__ Hbuf) {
  int c = blockIdx.x & 15, bh = blockIdx.x >> 4;
  int b = bh / NH, h = bh - b * NH;
  int t = threadIdx.x, w = t >> 6, l = t & 63;
  __shared__ float sTmp[64][65];
  __shared__ u16 sBT[64 * 64];
  __shared__ u16 sXT[64 * 64];
  __shared__ float sRatio[64];
  int m0 = b * SEQ + c * CLEN;
  if (w == 0) {
    float v = Abuf[(size_t)(m0 + l) * NH + h];
#pragma unroll
    for (int o = 1; o < 64; o <<= 1) {
      float u = __shfl_up(v, o);
      if (l >= o) v += u;
    }
    Lbuf[(size_t)(m0 + l) * NH + h] = v;
    float L63 = __shfl(v, 63);
    sRatio[l] = expf(L63 - v);
  }
  int rr = t >> 2, q = t & 3;
  {  // stage rope'd B -> sTmp (f32)
    const float* row = proj + (size_t)(m0 + rr) * PP + 3072 + h * 64;
    const float* ang = dtheta + (size_t)(m0 + rr) * 768 + h * 32;
    const float* angc = ctot + ((size_t)(b * NCHUNK + c)) * 768 + h * 32;
#pragma unroll
    for (int k = 0; k < 4; ++k) {
      int e = q * 16 + k * 4;
      float4 v = *(const float4*)(row + e);
      int j0 = e >> 1;
      float s0, c0, s1, c1;
      sincosf(ang[j0] + angc[j0], &s0, &c0);
      sincosf(ang[j0 + 1] + angc[j0 + 1], &s1, &c1);
      float4 ov;
      ov.x = c0 * v.x - s0 * v.y; ov.y = s0 * v.x + c0 * v.y;
      ov.z = c1 * v.z - s1 * v.w; ov.w = s1 * v.z + c1 * v.w;
      *(float4*)&sTmp[rr][e] = ov;
    }
  }
  __syncthreads();
  {  // transpose -> sBT[n][t] bf16, rotation + swizzle
#pragma unroll
    for (int k = 0; k < 8; ++k) {
      int tw = (l + w * 8 + k) & 31;
      int t0 = tw * 2;
      unsigned pk = (unsigned)f2bf(sTmp[t0][l]) | ((unsigned)f2bf(sTmp[t0 + 1][l]) << 16);
      *(unsigned*)(sBT + l * 64 + swz_idx(l, t0)) = pk;
    }
  }
  __syncthreads();
  {  // stage xs -> sTmp
    const float* row = proj + (size_t)(m0 + rr) * PP + 1536 + h * 64;
#pragma unroll
    for (int k = 0; k < 4; ++k) {
      int e = q * 16 + k * 4;
      *(float4*)&sTmp[rr][e] = *(const float4*)(row + e);
    }
  }
  __syncthreads();
  {  // transpose + ratio-scale -> sXT[p][t]
#pragma unroll
    for (int k = 0; k < 8; ++k) {
      int tw = (l + w * 8 + k) & 31;
      int t0 = tw * 2;
      float v0 = sTmp[t0][l] * sRatio[t0];
      float v1 = sTmp[t0 + 1][l] * sRatio[t0 + 1];
      unsigned pk = (unsigned)f2bf(v0) | ((unsigned)f2bf(v1) << 16);
      *(unsigned*)(sXT + l * 64 + swz_idx(l, t0)) = pk;
    }
  }
  __syncthreads();
  f32x4 acc[4] = {};
#pragma unroll
  for (int kh = 0; kh < 2; ++kh) {
    int cb = kh * 4 + (l >> 4);
    short8 af = frag(sXT, w * 16 + (l & 15), cb);
#pragma unroll
    for (int j = 0; j < 4; ++j)
      acc[j] = __builtin_amdgcn_mfma_f32_16x16x32_bf16(af, frag(sBT, j * 16 + (l & 15), cb), acc[j], 0, 0, 0);
  }
  float* Hp = Hbuf + ((size_t)(bh * NCHUNK + c)) * 4096;
  int pr = w * 16 + ((l >> 4) << 2);
#pragma unroll
  for (int j = 0; j < 4; ++j)
#pragma unroll
    for (int r = 0; r < 4; ++r)
      Hp[(size_t)(pr + r) * 64 + j * 16 + (l & 15)] = acc[j][r];
}

// ---------------- scan phase 2: chunk-level recurrence; Hbuf becomes H_in ---
__global__ __launch_bounds__(256) void scan2_kernel(
    float* __restrict__ Hbuf, const float* __restrict__ Lbuf) {
  int bh = blockIdx.x;
  int b = bh / NH, h = bh - b * NH;
  int e = threadIdx.x * 16;
  float S[16];
#pragma unroll
  for (int j = 0; j < 16; ++j) S[j] = 0.f;
  for (int c = 0; c < NCHUNK; ++c) {
    float* Hp = Hbuf + ((size_t)(bh * NCHUNK + c)) * 4096 + e;
    float P = expf(Lbuf[(size_t)(b * SEQ + c * CLEN + CLEN - 1) * NH + h]);
#pragma unroll
    for (int j = 0; j < 16; j += 4) {
      float4 loc = *(float4*)(Hp + j);
      float4 sv; sv.x = S[j]; sv.y = S[j + 1]; sv.z = S[j + 2]; sv.w = S[j + 3];
      *(float4*)(Hp + j) = sv;
      S[j]     = P * S[j]     + loc.x;
      S[j + 1] = P * S[j + 1] + loc.y;
      S[j + 2] = P * S[j + 2] + loc.z;
      S[j + 3] = P * S[j + 3] + loc.w;
    }
  }
}

// ---------------- kernel B: G=C.B^T, mask, Y = Gm@xs + e^L (C@Hin^T),
//                  + skip, * silu(z) -> actb (bf16). Rope on the fly. -------
__global__ __launch_bounds__(256) void intraB_kernel(
    const float* __restrict__ proj, const float* __restrict__ Hbuf,
    const float* __restrict__ Lbuf, const float* __restrict__ skip_b,
    const float* __restrict__ dtheta, const float* __restrict__ ctot,
    u16* __restrict__ actb) {
  int c = blockIdx.x & 15, bh = blockIdx.x >> 4;
  int b = bh / NH, h = bh - b * NH;
  int t = threadIdx.x, w = t >> 6, l = t & 63;
  __shared__ u16 sC[64 * 64];
  __shared__ u16 sBH[64 * 64];
  __shared__ u16 sXT[64 * 64];
  __shared__ union UU { float tmp[64][65]; u16 gm[64 * 64]; } uS;
  __shared__ float sL[64], sSkip[64];
  int m0 = b * SEQ + c * CLEN;
  if (w == 0) {
    sL[l] = Lbuf[(size_t)(m0 + l) * NH + h];
    sSkip[l] = skip_b[(size_t)(m0 + l) * NH + h];
  }
  int rr = t >> 2, q = t & 3;
  const float* ang = dtheta + (size_t)(m0 + rr) * 768 + h * 32;
  const float* angc = ctot + ((size_t)(b * NCHUNK + c)) * 768 + h * 32;
  {  // stage rope'd C -> sC (bf16 swizzled), xs -> uS.tmp (f32)
    const float* rowC = proj + (size_t)(m0 + rr) * PP + 4608 + h * 64;
    const float* rowX = proj + (size_t)(m0 + rr) * PP + 1536 + h * 64;
#pragma unroll
    for (int k = 0; k < 4; ++k) {
      int e = q * 16 + k * 4;
      float4 v = *(const float4*)(rowC + e);
      int j0 = e >> 1;
      float s0, c0, s1, c1;
      sincosf(ang[j0] + angc[j0], &s0, &c0);
      sincosf(ang[j0 + 1] + angc[j0 + 1], &s1, &c1);
      unsigned lo = (unsigned)f2bf(c0 * v.x - s0 * v.y) | ((unsigned)f2bf(s0 * v.x + c0 * v.y) << 16);
      unsigned hi = (unsigned)f2bf(c1 * v.z - s1 * v.w) | ((unsigned)f2bf(s1 * v.z + c1 * v.w) << 16);
      int idx = swz_idx(rr, e);
      *(unsigned*)(sC + rr * 64 + idx) = lo;
      *(unsigned*)(sC + rr * 64 + idx + 2) = hi;
      *(float4*)&uS.tmp[rr][e] = *(const float4*)(rowX + e);
    }
  }
  __syncthreads();
  {  // build sXT from tmp; stage rope'd B -> sBH
#pragma unroll
    for (int k = 0; k < 8; ++k) {
      int tw = (l + w * 8 + k) & 31;
      int t0 = tw * 2;
      unsigned pk = (unsigned)f2bf(uS.tmp[t0][l]) | ((unsigned)f2bf(uS.tmp[t0 + 1][l]) << 16);
      *(unsigned*)(sXT + l * 64 + swz_idx(l, t0)) = pk;
    }
    const float* rowB = proj + (size_t)(m0 + rr) * PP + 3072 + h * 64;
#pragma unroll
    for (int k = 0; k < 4; ++k) {
      int e = q * 16 + k * 4;
      float4 v = *(const float4*)(rowB + e);
      int j0 = e >> 1;
      float s0, c0, s1, c1;
      sincosf(ang[j0] + angc[j0], &s0, &c0);
      sincosf(ang[j0 + 1] + angc[j0 + 1], &s1, &c1);
      unsigned lo = (unsigned)f2bf(c0 * v.x - s0 * v.y) | ((unsigned)f2bf(s0 * v.x + c0 * v.y) << 16);
      unsigned hi = (unsigned)f2bf(c1 * v.z - s1 * v.w) | ((unsigned)f2bf(s1 * v.z + c1 * v.w) << 16);
      int idx = swz_idx(rr, e);
      *(unsigned*)(sBH + rr * 64 + idx) = lo;
      *(unsigned*)(sBH + rr * 64 + idx + 2) = hi;
    }
  }
  __syncthreads();
  // G = C . B^T  (k = n)
  f32x4 g4[4] = {};
#pragma unroll
  for (int kh = 0; kh < 2; ++kh) {
    int cb = kh * 4 + (l >> 4);
    short8 af = frag(sC, w * 16 + (l & 15), cb);
#pragma unroll
    for (int j = 0; j < 4; ++j)
      g4[j] = __builtin_amdgcn_mfma_f32_16x16x32_bf16(af, frag(sBH, j * 16 + (l & 15), cb), g4[j], 0, 0, 0);
  }
  __syncthreads();
  {  // mask + decay -> uS.gm ; stage H_in -> sBH
    int sr = w * 16 + ((l >> 4) << 2);
#pragma unroll
    for (int j = 0; j < 4; ++j) {
      int tc = j * 16 + (l & 15);
#pragma unroll
      for (int r = 0; r < 4; ++r) {
        int s = sr + r;
        float gv = (tc <= s) ? g4[j][r] * expf(sL[s] - sL[tc]) : 0.f;
        uS.gm[s * 64 + swz_idx(s, tc)] = f2bf(gv);
      }
    }
    const float* Hp = Hbuf + ((size_t)(bh * NCHUNK + c)) * 4096 + rr * 64;
#pragma unroll
    for (int k = 0; k < 4; ++k) {
      int e = q * 16 + k * 4;
      float4 v = *(const float4*)(Hp + e);
      unsigned lo = (unsigned)f2bf(v.x) | ((unsigned)f2bf(v.y) << 16);
      unsigned hi = (unsigned)f2bf(v.z) | ((unsigned)f2bf(v.w) << 16);
      int idx = swz_idx(rr, e);
      *(unsigned*)(sBH + rr * 64 + idx) = lo;
      *(unsigned*)(sBH + rr * 64 + idx + 2) = hi;
    }
  }
  __syncthreads();
  // Y1 = Gm @ xs (k = t), Y2 = C @ Hin^T (k = n)
  f32x4 y1[4] = {}, y2[4] = {};
#pragma unroll
  for (int kh = 0; kh < 2; ++kh) {
    int cb = kh * 4 + (l >> 4);
    short8 ag = frag(uS.gm, w * 16 + (l & 15), cb);
    short8 ac = frag(sC, w * 16 + (l & 15), cb);
#pragma unroll
    for (int j = 0; j < 4; ++j) {
      y1[j] = __builtin_amdgcn_mfma_f32_16x16x32_bf16(ag, frag(sXT, j * 16 + (l & 15), cb), y1[j], 0, 0, 0);
      y2[j] = __builtin_amdgcn_mfma_f32_16x16x32_bf16(ac, frag(sBH, j * 16 + (l & 15), cb), y2[j], 0, 0, 0);
    }
  }
  // epilogue: y + skip, * silu(z) -> actb
  int sr = w * 16 + ((l >> 4) << 2);
#pragma unroll
  for (int r = 0; r < 4; ++r) {
    int s = sr + r;
    float scale = expf(sL[s]);
    float skp = sSkip[s];
    size_t mrow = (size_t)(m0 + s);
#pragma unroll
    for (int j = 0; j < 4; ++j) {
      int p = j * 16 + (l & 15);
      float y = y1[j][r] + scale * y2[j][r] + skp;
      float z = proj[mrow * PP + h * 64 + p];
      float sg = 1.f / (1.f + expf(-z));
      actb[mrow * DINNER + h * 64 + p] = f2bf(y * z * sg);
    }
  }
}

// ---------------- glu: silu(g)*u -> bf16 (g,u stacked per row) --------------
__global__ void glu_kernel(const float* __restrict__ gu_all, u16* __restrict__ gub) {
  int i = blockIdx.x * 256 + threadIdx.x;   // < M*DMLP
  int m = i / DMLP;
  int ci = i - m * DMLP;
  float gv = gu_all[(size_t)m * 2 * DMLP + ci];
  float uv = gu_all[(size_t)m * 2 * DMLP + DMLP + ci];
  float s = gv / (1.f + expf(-gv));
  gub[i] = f2bf(s * uv);
}

extern "C" void kernel_launch(void* const* d_in, const int* in_sizes, int n_in,
                              void* d_out, int out_size, void* d_ws, size_t ws_size,
                              hipStream_t stream) {
  (void)in_sizes; (void)n_in; (void)out_size; (void)ws_size;
  const float* x      = (const float*)d_in[0];
  const float* n1w    = (const float*)d_in[1];
  const float* n2w    = (const float*)d_in[2];
  const float* w_in   = (const float*)d_in[3];
  const float* w_out  = (const float*)d_in[4];
  const float* A_log  = (const float*)d_in[5];
  const float* Dv     = (const float*)d_in[6];
  const float* dt_b   = (const float*)d_in[7];
  const float* B_bias = (const float*)d_in[8];
  const float* C_bias = (const float*)d_in[9];
  const float* Bnw    = (const float*)d_in[10];
  const float* Cnw    = (const float*)d_in[11];
  const float* w_g    = (const float*)d_in[12];
  const float* w_u    = (const float*)d_in[13];
  const float* w_d    = (const float*)d_in[14];
  float* out = (float*)d_out;

  char* ws = (char*)d_ws;
  size_t off = 0;
  auto alloc = [&](size_t bytes) -> char* {
    char* p = ws + off;
    off = (off + bytes + 255) & ~(size_t)255;
    return p;
  };
  u16*   wb_in  = (u16*)  alloc(E0 * 2);
  u16*   wb_out = (u16*)  alloc(E1 * 2);
  u16*   wb_gu  = (u16*)  alloc(E2 * 2 * 2);
  u16*   wb_d   = (u16*)  alloc(E2 * 2);
  u16*   h1     = (u16*)  alloc((size_t)MROWS * DMODEL * 2);
  float* proj   = (float*)alloc((size_t)MROWS * PP * 4);
  float* Abuf   = (float*)alloc((size_t)MROWS * NH * 4);
  float* skip_b = (float*)alloc((size_t)MROWS * NH * 4);
  float* Lbuf   = (float*)alloc((size_t)MROWS * NH * 4);
  float* dtheta = (float*)alloc((size_t)MROWS * 768 * 4);
  float* ctot   = (float*)alloc((size_t)B_N * NCHUNK * 768 * 4);
  float* Hbuf   = (float*)alloc((size_t)B_N * NH * NCHUNK * 4096 * 4);
  u16*   actb   = (u16*)  alloc((size_t)MROWS * DINNER * 2);
  float* tmp1   = (float*)alloc((size_t)MROWS * DMODEL * 4);
  float* x2     = (float*)alloc((size_t)MROWS * DMODEL * 4);
  u16*   h2     = (u16*)  alloc((size_t)MROWS * DMODEL * 2);
  // MLP buffers overlay proj (dead after intraB)
  float* gu_all = proj;
  u16*   gub    = (u16*)(proj + (size_t)MROWS * 2 * DMLP);
  float* mlpbuf = (float*)((char*)gub + (size_t)MROWS * DMLP * 2 + 256);
  (void)mlpbuf;

  cast_all_kernel<<<(int)((ETOT / 4 + 255) / 256), 256, 0, stream>>>(
      w_in, w_out, w_g, w_u, w_d, wb_in, wb_out, wb_gu, wb_d);
  add_rmsnorm_kernel<<<MROWS, 256, 0, stream>>>(x, nullptr, n1w, nullptr, h1);
  {
    dim3 g(PP / 128, MROWS / 128);
    gemm_bt_kernel<128><<<g, 256, 0, stream>>>(h1, wb_in, proj, DMODEL, PP, nullptr);
  }
  prep_kernel<<<MROWS * NH / 4, 256, 0, stream>>>(proj, A_log, Dv, dt_b, B_bias, C_bias,
                                                  Bnw, Cnw, Abuf, skip_b, dtheta);
  cumsum_a_kernel<<<B_N * NCHUNK * 3, 256, 0, stream>>>(dtheta, ctot);
  cumsum_b_kernel<<<6, 256, 0, stream>>>(ctot);
  houtA_kernel<<<B_N * NH * NCHUNK, 256, 0, stream>>>(proj, Abuf, dtheta, ctot, Lbuf, Hbuf);
  scan2_kernel<<<B_N * NH, 256, 0, stream>>>(Hbuf, Lbuf);
  intraB_kernel<<<B_N * NH * NCHUNK, 256, 0, stream>>>(proj, Hbuf, Lbuf, skip_b,
                                                       dtheta, ctot, actb);
  {
    dim3 g(DMODEL / 128, MROWS / 64);
    gemm_bt_kernel<64><<<g, 256, 0, stream>>>(actb, wb_out, tmp1, DINNER, DMODEL, nullptr);
  }
  add_rmsnorm_kernel<<<MROWS, 256, 0, stream>>>(x, tmp1, n2w, x2, h2);
  {
    dim3 g(2 * DMLP / 128, MROWS / 128);
    gemm_bt_kernel<128><<<g, 256, 0, stream>>>(h2, wb_gu, gu_all, DMODEL, 2 * DMLP, nullptr);
  }
  glu_kernel<<<MROWS * DMLP / 256, 256, 0, stream>>>(gu_all, gub);
  {
    dim3 g(DMODEL / 128, MROWS / 64);
    gemm_bt_kernel<64><<<g, 256, 0, stream>>>(gub, wb_d, out, DMLP, DMODEL, x2);
  }
}

// Round 4
// 333.499 us; speedup vs baseline: 1.4848x; 1.0232x over previous
//
#include <hip/hip_runtime.h>

typedef unsigned short u16;
typedef __attribute__((ext_vector_type(8))) short short8;
typedef __attribute__((ext_vector_type(4))) float f32x4;

constexpr int B_N    = 2;
constexpr int SEQ    = 1024;
constexpr int DMODEL = 768;
constexpr int DINNER = 1536;
constexpr int NH     = 24;
constexpr int DMLP   = 1920;
constexpr int NPROJ  = 6936;
constexpr int PP     = 7040;          // padded proj width (55*128)
constexpr int MROWS  = B_N * SEQ;     // 2048
constexpr int NCHUNK = 16;
constexpr int CLEN   = 64;

__device__ __forceinline__ u16 f2bf(float f) {
  union { float f; unsigned u; } x; x.f = f;
  unsigned r = x.u + 0x7fffu + ((x.u >> 16) & 1u);
  return (u16)(r >> 16);
}
__device__ __forceinline__ float bf2f(u16 b) {
  union { unsigned u; float f; } x; x.u = ((unsigned)b) << 16; return x.f;
}

__device__ __forceinline__ void gld_lds16(const u16* g, u16* l) {
  __builtin_amdgcn_global_load_lds((const __attribute__((address_space(1))) void*)g,
                                   (__attribute__((address_space(3))) void*)l, 16, 0, 0);
}

// swizzled bf16 fragment read: 8 consecutive (swizzled) elements at (row, colblock cb)
__device__ __forceinline__ short8 frag(const u16* base, int row, int cb) {
  return *(const short8*)(base + row * 64 + ((cb ^ (row & 7)) << 3));
}
__device__ __forceinline__ int swz_idx(int row, int e) {
  return (((e >> 3) ^ (row & 7)) << 3) | (e & 7);
}

// ---------------- one cast kernel for all weights (f32 -> bf16) -------------
constexpr size_t E0  = (size_t)PP * DMODEL;
constexpr size_t E0s = (size_t)NPROJ * DMODEL;
constexpr size_t E1  = (size_t)DMODEL * DINNER;
constexpr size_t E2  = (size_t)DMLP * DMODEL;
constexpr size_t ETOT = E0 + E1 + 3 * E2;

__global__ void cast_all_kernel(const float* __restrict__ w_in, const float* __restrict__ w_out,
                                const float* __restrict__ w_g, const float* __restrict__ w_u,
                                const float* __restrict__ w_d,
                                u16* __restrict__ wb_in, u16* __restrict__ wb_out,
                                u16* __restrict__ wb_gu, u16* __restrict__ wb_d) {
  size_t i = ((size_t)blockIdx.x * 256 + threadIdx.x) * 4;
  if (i >= ETOT) return;
  float4 v; u16* dst;
  if (i < E0) {
    dst = wb_in + i;
    if (i < E0s) v = *(const float4*)(w_in + i);
    else { v.x = v.y = v.z = v.w = 0.f; }
  } else if (i < E0 + E1) {
    size_t k = i - E0; dst = wb_out + k; v = *(const float4*)(w_out + k);
  } else if (i < E0 + E1 + 2 * E2) {
    // interleaved gate/up: row 2j = gate_j, row 2j+1 = up_j
    size_t k = i - E0 - E1;
    size_t r = k / DMODEL, col = k - r * DMODEL;
    const float* src = (r & 1) ? w_u : w_g;
    v = *(const float4*)(src + (r >> 1) * DMODEL + col);
    dst = wb_gu + k;
  } else {
    size_t k = i - E0 - E1 - 2 * E2; dst = wb_d + k; v = *(const float4*)(w_d + k);
  }
  short4 o;
  o.x = (short)f2bf(v.x); o.y = (short)f2bf(v.y);
  o.z = (short)f2bf(v.z); o.w = (short)f2bf(v.w);
  *(short4*)dst = o;
}

// ---------------- fused (a [+ b]) -> rmsnorm -> bf16 ; optional raw-sum out --
__global__ __launch_bounds__(256) void add_rmsnorm_kernel(
    const float* __restrict__ a, const float* __restrict__ b,
    const float* __restrict__ w, float* __restrict__ sum_out,
    u16* __restrict__ hout) {
  int row = blockIdx.x;
  int t = threadIdx.x;
  const float* pa = a + (size_t)row * DMODEL;
  const float* pb = b ? b + (size_t)row * DMODEL : nullptr;
  float v[3]; float ss = 0.f;
#pragma unroll
  for (int i = 0; i < 3; ++i) {
    int c = t + i * 256;
    float x = pa[c];
    if (pb) x += pb[c];
    v[i] = x; ss += x * x;
  }
#pragma unroll
  for (int o = 32; o > 0; o >>= 1) ss += __shfl_xor(ss, o);
  __shared__ float red[4];
  if ((t & 63) == 0) red[t >> 6] = ss;
  __syncthreads();
  ss = red[0] + red[1] + red[2] + red[3];
  float sc = rsqrtf(ss * (1.f / DMODEL) + 1e-5f);
#pragma unroll
  for (int i = 0; i < 3; ++i) {
    int c = t + i * 256;
    if (sum_out) sum_out[(size_t)row * DMODEL + c] = v[i];
    hout[(size_t)row * DMODEL + c] = f2bf(v[i] * sc * w[c]);
  }
}

// ---------------- bf16 MFMA GEMM: C = A * B^T --------------------------------
// MODE 0: f32 out (+optional addsrc). MODE 1: bf16 out. MODE 2: glu-paired
// bf16 out (even col = gate, odd col = up; writes silu(g)*u at col n/2,
// output stride ldc).
template<int BM, int MODE>
__global__ __launch_bounds__(256) void gemm_bt_kernel(
    const u16* __restrict__ A, const u16* __restrict__ Bw,
    void* __restrict__ Cv, int K, int ldc, const float* __restrict__ addsrc) {
  constexpr int MI = BM / 32;
  __shared__ u16 As[BM * 64];
  __shared__ u16 Bs[128 * 64];
  const int t = threadIdx.x;
  const int lane = t & 63;
  const int wave = t >> 6;
  const int wm = wave >> 1, wn = wave & 1;
  const int gx = gridDim.x, gy = gridDim.y;
  const int o = blockIdx.y * gx + blockIdx.x;
  const int nwg = gx * gy;
  const int cid = (o & 7) * (nwg >> 3) + (o >> 3);
  const int bx = cid / gy, by = cid - bx * gy;
  const int m0 = by * BM, n0 = bx * 128;
  f32x4 acc[MI][4] = {};
  const int rr = t >> 3;
  const int kc = (t & 7) * 8;
  const u16* ga = A + (size_t)(m0 + rr) * K + kc;
  const u16* gb = Bw + (size_t)(n0 + rr) * K + kc;
  for (int kt = 0; kt < K; kt += 64) {
    __syncthreads();
#pragma unroll
    for (int i = 0; i < MI; ++i)
      gld_lds16(ga + (size_t)i * 32 * K + kt, As + i * 2048 + t * 8);
#pragma unroll
    for (int i = 0; i < 4; ++i)
      gld_lds16(gb + (size_t)i * 32 * K + kt, Bs + i * 2048 + t * 8);
    __syncthreads();
#pragma unroll
    for (int kh = 0; kh < 2; ++kh) {
      short8 af[MI], bfr[4];
#pragma unroll
      for (int i = 0; i < MI; ++i)
        af[i] = *(const short8*)(As + (wm * (BM / 2) + i * 16 + (lane & 15)) * 64 + kh * 32 + (lane >> 4) * 8);
#pragma unroll
      for (int j = 0; j < 4; ++j)
        bfr[j] = *(const short8*)(Bs + (wn * 64 + j * 16 + (lane & 15)) * 64 + kh * 32 + (lane >> 4) * 8);
#pragma unroll
      for (int i = 0; i < MI; ++i)
#pragma unroll
        for (int j = 0; j < 4; ++j)
          acc[i][j] = __builtin_amdgcn_mfma_f32_16x16x32_bf16(af[i], bfr[j], acc[i][j], 0, 0, 0);
    }
  }
  const int cr = (lane >> 4) * 4;
  const int cc = lane & 15;
#pragma unroll
  for (int i = 0; i < MI; ++i) {
#pragma unroll
    for (int j = 0; j < 4; ++j) {
      int row = m0 + wm * (BM / 2) + i * 16 + cr;
      int col = n0 + wn * 64 + j * 16 + cc;
      if (MODE == 0) {
        float* C = (float*)Cv;
        float* cp = C + (size_t)row * ldc + col;
        if (addsrc) {
          const float* ap = addsrc + (size_t)row * ldc + col;
#pragma unroll
          for (int r = 0; r < 4; ++r) cp[(size_t)r * ldc] = acc[i][j][r] + ap[(size_t)r * ldc];
        } else {
#pragma unroll
          for (int r = 0; r < 4; ++r) cp[(size_t)r * ldc] = acc[i][j][r];
        }
      } else if (MODE == 1) {
        u16* C = (u16*)Cv;
#pragma unroll
        for (int r = 0; r < 4; ++r)
          C[(size_t)(row + r) * ldc + col] = f2bf(acc[i][j][r]);
      } else {
        u16* C = (u16*)Cv;
#pragma unroll
        for (int r = 0; r < 4; ++r) {
          float v = acc[i][j][r];
          float p = __shfl_xor(v, 1);
          if ((lane & 1) == 0) {
            float g = v, u = p;
            float res = g / (1.f + expf(-g)) * u;
            C[(size_t)(row + r) * ldc + (col >> 1)] = f2bf(res);
          }
        }
      }
    }
  }
}

// ---------------- prep: B/C rmsnorm+bias (in place, bf16), A=log(alpha),
//                  skip, dtheta, pre-scale x_ssm by gamma. One wave/(m,h). --
__global__ __launch_bounds__(256) void prep_kernel(
    u16* __restrict__ proj, const float* __restrict__ A_log,
    const float* __restrict__ Dv, const float* __restrict__ dt_bias,
    const float* __restrict__ B_bias, const float* __restrict__ C_bias,
    const float* __restrict__ Bnw, const float* __restrict__ Cnw,
    float* __restrict__ Abuf, float* __restrict__ skip_b,
    float* __restrict__ dtheta) {
  int wid = blockIdx.x * 4 + (threadIdx.x >> 6);
  int lane = threadIdx.x & 63;
  int m = wid / NH, h = wid - m * NH;
  u16* row = proj + (size_t)m * PP;

  float Braw = bf2f(row[3072 + h * 64 + lane]);
  float Craw = bf2f(row[4608 + h * 64 + lane]);
  float sb = Braw * Braw, sc2 = Craw * Craw;
#pragma unroll
  for (int o = 32; o > 0; o >>= 1) { sb += __shfl_xor(sb, o); sc2 += __shfl_xor(sc2, o); }
  float rb = rsqrtf(sb * (1.f / 64.f) + 1e-5f);
  float rc = rsqrtf(sc2 * (1.f / 64.f) + 1e-5f);
  row[3072 + h * 64 + lane] = f2bf(Braw * rb * Bnw[lane] + B_bias[h * 64 + lane]);
  row[4608 + h * 64 + lane] = f2bf(Craw * rc * Cnw[lane] + C_bias[h * 64 + lane]);

  float dtr = bf2f(row[6144 + h]) + dt_bias[h];
  float dt = dtr > 20.f ? dtr : log1pf(expf(dtr));
  float A = -expf(A_log[h]) * dt;
  float alpha = expf(A);
  float gamma = (alpha - 1.f) / (A + 1e-6f) * 0.5f + 1.f;

  float xv = bf2f(row[1536 + h * 64 + lane]);
  float sx = xv;
#pragma unroll
  for (int o = 32; o > 0; o >>= 1) sx += __shfl_xor(sx, o);
  row[1536 + h * 64 + lane] = f2bf(xv * gamma);   // pre-scale for scan

  if (lane == 0) {
    Abuf[(size_t)m * NH + h] = A;           // log(alpha)
    skip_b[(size_t)m * NH + h] = Dv[h] * sx;
  }
  if (lane < 32) {
    float th = bf2f(row[6168 + h * 32 + lane]);
    dtheta[(size_t)m * 768 + h * 32 + lane] = dt * th;
  }
}

// ---------------- chunked cumsum of dtheta over s ---------------------------
__global__ __launch_bounds__(256) void cumsum_a_kernel(float* __restrict__ dtheta,
                                                       float* __restrict__ ctot) {
  int bid = blockIdx.x;                  // 96 = 2 * 16 * 3
  int cb = bid % 3, rest = bid / 3;
  int c = rest & 15, b = rest >> 4;
  int col = cb * 256 + threadIdx.x;
  float* p = dtheta + ((size_t)(b * SEQ + c * CLEN)) * 768 + col;
  float acc = 0.f;
#pragma unroll 4
  for (int s = 0; s < CLEN; ++s) {
    acc += p[(size_t)s * 768];
    p[(size_t)s * 768] = acc;
  }
  ctot[((size_t)b * NCHUNK + c) * 768 + col] = acc;
}

__global__ void cumsum_b_kernel(float* __restrict__ ctot) {
  int tid = blockIdx.x * 256 + threadIdx.x;   // < 1536
  int b = tid / 768, col = tid - b * 768;
  float pre = 0.f;
#pragma unroll
  for (int c = 0; c < NCHUNK; ++c) {
    size_t o = ((size_t)b * NCHUNK + c) * 768 + col;
    float v = ctot[o];
    ctot[o] = pre;
    pre += v;
  }
}

// ---------------- kernel A: H_out[p][n] = sum_t ratio[t] * xs[t,p] * B[t,n] --
__global__ __launch_bounds__(256) void houtA_kernel(
    const u16* __restrict__ proj, const float* __restrict__ Abuf,
    const float* __restrict__ dtheta, const float* __restrict__ ctot,
    float* __restrict__ Lbuf, float* __restrict__ Hbuf) {
  int c = blockIdx.x & 15, bh = blockIdx.x >> 4;
  int b = bh / NH, h = bh - b * NH;
  int t = threadIdx.x, w = t >> 6, l = t & 63;
  __shared__ float sTmp[64][65];
  __shared__ u16 sBT[64 * 64];
  __shared__ u16 sXT[64 * 64];
  __shared__ float sRatio[64];
  int m0 = b * SEQ + c * CLEN;
  if (w == 0) {
    float v = Abuf[(size_t)(m0 + l) * NH + h];
#pragma unroll
    for (int o = 1; o < 64; o <<= 1) {
      float u = __shfl_up(v, o);
      if (l >= o) v += u;
    }
    Lbuf[(size_t)(m0 + l) * NH + h] = v;
    float L63 = __shfl(v, 63);
    sRatio[l] = expf(L63 - v);
  }
  int rr = t >> 2, q = t & 3;
  {  // stage rope'd B -> sTmp (f32)
    const u16* row = proj + (size_t)(m0 + rr) * PP + 3072 + h * 64;
    const float* ang = dtheta + (size_t)(m0 + rr) * 768 + h * 32;
    const float* angc = ctot + ((size_t)(b * NCHUNK + c)) * 768 + h * 32;
#pragma unroll
    for (int k = 0; k < 4; ++k) {
      int e = q * 16 + k * 4;
      short4 sv = *(const short4*)(row + e);
      int j0 = e >> 1;
      float s0, c0, s1, c1;
      sincosf(ang[j0] + angc[j0], &s0, &c0);
      sincosf(ang[j0 + 1] + angc[j0 + 1], &s1, &c1);
      float vx = bf2f((u16)sv.x), vy = bf2f((u16)sv.y);
      float vz = bf2f((u16)sv.z), vw = bf2f((u16)sv.w);
      float4 ov;
      ov.x = c0 * vx - s0 * vy; ov.y = s0 * vx + c0 * vy;
      ov.z = c1 * vz - s1 * vw; ov.w = s1 * vz + c1 * vw;
      *(float4*)&sTmp[rr][e] = ov;
    }
  }
  __syncthreads();
  {  // transpose -> sBT[n][t] bf16, rotation + swizzle
#pragma unroll
    for (int k = 0; k < 8; ++k) {
      int tw = (l + w * 8 + k) & 31;
      int t0 = tw * 2;
      unsigned pk = (unsigned)f2bf(sTmp[t0][l]) | ((unsigned)f2bf(sTmp[t0 + 1][l]) << 16);
      *(unsigned*)(sBT + l * 64 + swz_idx(l, t0)) = pk;
    }
  }
  __syncthreads();
  {  // stage xs -> sTmp
    const u16* row = proj + (size_t)(m0 + rr) * PP + 1536 + h * 64;
#pragma unroll
    for (int k = 0; k < 4; ++k) {
      int e = q * 16 + k * 4;
      short4 sv = *(const short4*)(row + e);
      float4 ov;
      ov.x = bf2f((u16)sv.x); ov.y = bf2f((u16)sv.y);
      ov.z = bf2f((u16)sv.z); ov.w = bf2f((u16)sv.w);
      *(float4*)&sTmp[rr][e] = ov;
    }
  }
  __syncthreads();
  {  // transpose + ratio-scale -> sXT[p][t]
#pragma unroll
    for (int k = 0; k < 8; ++k) {
      int tw = (l + w * 8 + k) & 31;
      int t0 = tw * 2;
      float v0 = sTmp[t0][l] * sRatio[t0];
      float v1 = sTmp[t0 + 1][l] * sRatio[t0 + 1];
      unsigned pk = (unsigned)f2bf(v0) | ((unsigned)f2bf(v1) << 16);
      *(unsigned*)(sXT + l * 64 + swz_idx(l, t0)) = pk;
    }
  }
  __syncthreads();
  f32x4 acc[4] = {};
#pragma unroll
  for (int kh = 0; kh < 2; ++kh) {
    int cb = kh * 4 + (l >> 4);
    short8 af = frag(sXT, w * 16 + (l & 15), cb);
#pragma unroll
    for (int j = 0; j < 4; ++j)
      acc[j] = __builtin_amdgcn_mfma_f32_16x16x32_bf16(af, frag(sBT, j * 16 + (l & 15), cb), acc[j], 0, 0, 0);
  }
  float* Hp = Hbuf + ((size_t)(bh * NCHUNK + c)) * 4096;
  int pr = w * 16 + ((l >> 4) << 2);
#pragma unroll
  for (int j = 0; j < 4; ++j)
#pragma unroll
    for (int r = 0; r < 4; ++r)
      Hp[(size_t)(pr + r) * 64 + j * 16 + (l & 15)] = acc[j][r];
}

// ---------------- scan phase 2: chunk-level recurrence; Hbuf becomes H_in ---
__global__ __launch_bounds__(256) void scan2_kernel(
    float* __restrict__ Hbuf, const float* __restrict__ Lbuf) {
  int bh = blockIdx.x;
  int b = bh / NH, h = bh - b * NH;
  int e = threadIdx.x * 16;
  float S[16];
#pragma unroll
  for (int j = 0; j < 16; ++j) S[j] = 0.f;
  for (int c = 0; c < NCHUNK; ++c) {
    float* Hp = Hbuf + ((size_t)(bh * NCHUNK + c)) * 4096 + e;
    float P = expf(Lbuf[(size_t)(b * SEQ + c * CLEN + CLEN - 1) * NH + h]);
#pragma unroll
    for (int j = 0; j < 16; j += 4) {
      float4 loc = *(float4*)(Hp + j);
      float4 sv; sv.x = S[j]; sv.y = S[j + 1]; sv.z = S[j + 2]; sv.w = S[j + 3];
      *(float4*)(Hp + j) = sv;
      S[j]     = P * S[j]     + loc.x;
      S[j + 1] = P * S[j + 1] + loc.y;
      S[j + 2] = P * S[j + 2] + loc.z;
      S[j + 3] = P * S[j + 3] + loc.w;
    }
  }
}

// ---------------- kernel B: G=C.B^T, mask, Y = Gm@xs + e^L (C@Hin^T),
//                  + skip, * silu(z) -> actb (bf16). Rope on the fly. -------
__global__ __launch_bounds__(256) void intraB_kernel(
    const u16* __restrict__ proj, const float* __restrict__ Hbuf,
    const float* __restrict__ Lbuf, const float* __restrict__ skip_b,
    const float* __restrict__ dtheta, const float* __restrict__ ctot,
    u16* __restrict__ actb) {
  int c = blockIdx.x & 15, bh = blockIdx.x >> 4;
  int b = bh / NH, h = bh - b * NH;
  int t = threadIdx.x, w = t >> 6, l = t & 63;
  __shared__ u16 sC[64 * 64];
  __shared__ u16 sBH[64 * 64];
  __shared__ u16 sXT[64 * 64];
  __shared__ union UU { float tmp[64][65]; u16 gm[64 * 64]; } uS;
  __shared__ float sL[64], sSkip[64];
  int m0 = b * SEQ + c * CLEN;
  if (w == 0) {
    sL[l] = Lbuf[(size_t)(m0 + l) * NH + h];
    sSkip[l] = skip_b[(size_t)(m0 + l) * NH + h];
  }
  int rr = t >> 2, q = t & 3;
  const float* ang = dtheta + (size_t)(m0 + rr) * 768 + h * 32;
  const float* angc = ctot + ((size_t)(b * NCHUNK + c)) * 768 + h * 32;
  {  // stage rope'd C -> sC (bf16 swizzled), xs -> uS.tmp (f32)
    const u16* rowC = proj + (size_t)(m0 + rr) * PP + 4608 + h * 64;
    const u16* rowX = proj + (size_t)(m0 + rr) * PP + 1536 + h * 64;
#pragma unroll
    for (int k = 0; k < 4; ++k) {
      int e = q * 16 + k * 4;
      short4 sv = *(const short4*)(rowC + e);
      int j0 = e >> 1;
      float s0, c0, s1, c1;
      sincosf(ang[j0] + angc[j0], &s0, &c0);
      sincosf(ang[j0 + 1] + angc[j0 + 1], &s1, &c1);
      float vx = bf2f((u16)sv.x), vy = bf2f((u16)sv.y);
      float vz = bf2f((u16)sv.z), vw = bf2f((u16)sv.w);
      unsigned lo = (unsigned)f2bf(c0 * vx - s0 * vy) | ((unsigned)f2bf(s0 * vx + c0 * vy) << 16);
      unsigned hi = (unsigned)f2bf(c1 * vz - s1 * vw) | ((unsigned)f2bf(s1 * vz + c1 * vw) << 16);
      int idx = swz_idx(rr, e);
      *(unsigned*)(sC + rr * 64 + idx) = lo;
      *(unsigned*)(sC + rr * 64 + idx + 2) = hi;
      short4 xv = *(const short4*)(rowX + e);
      float4 ov;
      ov.x = bf2f((u16)xv.x); ov.y = bf2f((u16)xv.y);
      ov.z = bf2f((u16)xv.z); ov.w = bf2f((u16)xv.w);
      *(float4*)&uS.tmp[rr][e] = ov;
    }
  }
  __syncthreads();
  {  // build sXT from tmp; stage rope'd B -> sBH
#pragma unroll
    for (int k = 0; k < 8; ++k) {
      int tw = (l + w * 8 + k) & 31;
      int t0 = tw * 2;
      unsigned pk = (unsigned)f2bf(uS.tmp[t0][l]) | ((unsigned)f2bf(uS.tmp[t0 + 1][l]) << 16);
      *(unsigned*)(sXT + l * 64 + swz_idx(l, t0)) = pk;
    }
    const u16* rowB = proj + (size_t)(m0 + rr) * PP + 3072 + h * 64;
#pragma unroll
    for (int k = 0; k < 4; ++k) {
      int e = q * 16 + k * 4;
      short4 sv = *(const short4*)(rowB + e);
      int j0 = e >> 1;
      float s0, c0, s1, c1;
      sincosf(ang[j0] + angc[j0], &s0, &c0);
      sincosf(ang[j0 + 1] + angc[j0 + 1], &s1, &c1);
      float vx = bf2f((u16)sv.x), vy = bf2f((u16)sv.y);
      float vz = bf2f((u16)sv.z), vw = bf2f((u16)sv.w);
      unsigned lo = (unsigned)f2bf(c0 * vx - s0 * vy) | ((unsigned)f2bf(s0 * vx + c0 * vy) << 16);
      unsigned hi = (unsigned)f2bf(c1 * vz - s1 * vw) | ((unsigned)f2bf(s1 * vz + c1 * vw) << 16);
      int idx = swz_idx(rr, e);
      *(unsigned*)(sBH + rr * 64 + idx) = lo;
      *(unsigned*)(sBH + rr * 64 + idx + 2) = hi;
    }
  }
  __syncthreads();
  // G = C . B^T  (k = n)
  f32x4 g4[4] = {};
#pragma unroll
  for (int kh = 0; kh < 2; ++kh) {
    int cb = kh * 4 + (l >> 4);
    short8 af = frag(sC, w * 16 + (l & 15), cb);
#pragma unroll
    for (int j = 0; j < 4; ++j)
      g4[j] = __builtin_amdgcn_mfma_f32_16x16x32_bf16(af, frag(sBH, j * 16 + (l & 15), cb), g4[j], 0, 0, 0);
  }
  __syncthreads();
  {  // mask + decay -> uS.gm ; stage H_in -> sBH
    int sr = w * 16 + ((l >> 4) << 2);
#pragma unroll
    for (int j = 0; j < 4; ++j) {
      int tc = j * 16 + (l & 15);
#pragma unroll
      for (int r = 0; r < 4; ++r) {
        int s = sr + r;
        float gv = (tc <= s) ? g4[j][r] * expf(sL[s] - sL[tc]) : 0.f;
        uS.gm[s * 64 + swz_idx(s, tc)] = f2bf(gv);
      }
    }
    const float* Hp = Hbuf + ((size_t)(bh * NCHUNK + c)) * 4096 + rr * 64;
#pragma unroll
    for (int k = 0; k < 4; ++k) {
      int e = q * 16 + k * 4;
      float4 v = *(const float4*)(Hp + e);
      unsigned lo = (unsigned)f2bf(v.x) | ((unsigned)f2bf(v.y) << 16);
      unsigned hi = (unsigned)f2bf(v.z) | ((unsigned)f2bf(v.w) << 16);
      int idx = swz_idx(rr, e);
      *(unsigned*)(sBH + rr * 64 + idx) = lo;
      *(unsigned*)(sBH + rr * 64 + idx + 2) = hi;
    }
  }
  __syncthreads();
  // Y1 = Gm @ xs (k = t), Y2 = C @ Hin^T (k = n)
  f32x4 y1[4] = {}, y2[4] = {};
#pragma unroll
  for (int kh = 0; kh < 2; ++kh) {
    int cb = kh * 4 + (l >> 4);
    short8 ag = frag(uS.gm, w * 16 + (l & 15), cb);
    short8 ac = frag(sC, w * 16 + (l & 15), cb);
#pragma unroll
    for (int j = 0; j < 4; ++j) {
      y1[j] = __builtin_amdgcn_mfma_f32_16x16x32_bf16(ag, frag(sXT, j * 16 + (l & 15), cb), y1[j], 0, 0, 0);
      y2[j] = __builtin_amdgcn_mfma_f32_16x16x32_bf16(ac, frag(sBH, j * 16 + (l & 15), cb), y2[j], 0, 0, 0);
    }
  }
  // epilogue: y + skip, * silu(z) -> actb
  int sr = w * 16 + ((l >> 4) << 2);
#pragma unroll
  for (int r = 0; r < 4; ++r) {
    int s = sr + r;
    float scale = expf(sL[s]);
    float skp = sSkip[s];
    size_t mrow = (size_t)(m0 + s);
#pragma unroll
    for (int j = 0; j < 4; ++j) {
      int p = j * 16 + (l & 15);
      float y = y1[j][r] + scale * y2[j][r] + skp;
      float z = bf2f(proj[mrow * PP + h * 64 + p]);
      float sg = 1.f / (1.f + expf(-z));
      actb[mrow * DINNER + h * 64 + p] = f2bf(y * z * sg);
    }
  }
}

extern "C" void kernel_launch(void* const* d_in, const int* in_sizes, int n_in,
                              void* d_out, int out_size, void* d_ws, size_t ws_size,
                              hipStream_t stream) {
  (void)in_sizes; (void)n_in; (void)out_size; (void)ws_size;
  const float* x      = (const float*)d_in[0];
  const float* n1w    = (const float*)d_in[1];
  const float* n2w    = (const float*)d_in[2];
  const float* w_in   = (const float*)d_in[3];
  const float* w_out  = (const float*)d_in[4];
  const float* A_log  = (const float*)d_in[5];
  const float* Dv     = (const float*)d_in[6];
  const float* dt_b   = (const float*)d_in[7];
  const float* B_bias = (const float*)d_in[8];
  const float* C_bias = (const float*)d_in[9];
  const float* Bnw    = (const float*)d_in[10];
  const float* Cnw    = (const float*)d_in[11];
  const float* w_g    = (const float*)d_in[12];
  const float* w_u    = (const float*)d_in[13];
  const float* w_d    = (const float*)d_in[14];
  float* out = (float*)d_out;

  char* ws = (char*)d_ws;
  size_t off = 0;
  auto alloc = [&](size_t bytes) -> char* {
    char* p = ws + off;
    off = (off + bytes + 255) & ~(size_t)255;
    return p;
  };
  u16*   wb_in  = (u16*)  alloc(E0 * 2);
  u16*   wb_out = (u16*)  alloc(E1 * 2);
  u16*   wb_gu  = (u16*)  alloc(E2 * 2 * 2);      // interleaved gate/up rows
  u16*   wb_d   = (u16*)  alloc(E2 * 2);
  u16*   h1     = (u16*)  alloc((size_t)MROWS * DMODEL * 2);
  u16*   proj   = (u16*)  alloc((size_t)MROWS * PP * 2);
  float* Abuf   = (float*)alloc((size_t)MROWS * NH * 4);
  float* skip_b = (float*)alloc((size_t)MROWS * NH * 4);
  float* Lbuf   = (float*)alloc((size_t)MROWS * NH * 4);
  float* dtheta = (float*)alloc((size_t)MROWS * 768 * 4);
  float* ctot   = (float*)alloc((size_t)B_N * NCHUNK * 768 * 4);
  float* Hbuf   = (float*)alloc((size_t)B_N * NH * NCHUNK * 4096 * 4);
  u16*   actb   = (u16*)  alloc((size_t)MROWS * DINNER * 2);
  float* tmp1   = (float*)alloc((size_t)MROWS * DMODEL * 4);
  float* x2     = (float*)alloc((size_t)MROWS * DMODEL * 4);
  u16*   h2     = (u16*)  alloc((size_t)MROWS * DMODEL * 2);
  u16*   gub    = (u16*)  alloc((size_t)MROWS * DMLP * 2);

  cast_all_kernel<<<(int)((ETOT / 4 + 255) / 256), 256, 0, stream>>>(
      w_in, w_out, w_g, w_u, w_d, wb_in, wb_out, wb_gu, wb_d);
  add_rmsnorm_kernel<<<MROWS, 256, 0, stream>>>(x, nullptr, n1w, nullptr, h1);
  {  // in_proj -> proj (bf16)
    dim3 g(PP / 128, MROWS / 128);
    gemm_bt_kernel<128, 1><<<g, 256, 0, stream>>>(h1, wb_in, proj, DMODEL, PP, nullptr);
  }
  prep_kernel<<<MROWS * NH / 4, 256, 0, stream>>>(proj, A_log, Dv, dt_b, B_bias, C_bias,
                                                  Bnw, Cnw, Abuf, skip_b, dtheta);
  cumsum_a_kernel<<<B_N * NCHUNK * 3, 256, 0, stream>>>(dtheta, ctot);
  cumsum_b_kernel<<<6, 256, 0, stream>>>(ctot);
  houtA_kernel<<<B_N * NH * NCHUNK, 256, 0, stream>>>(proj, Abuf, dtheta, ctot, Lbuf, Hbuf);
  scan2_kernel<<<B_N * NH, 256, 0, stream>>>(Hbuf, Lbuf);
  intraB_kernel<<<B_N * NH * NCHUNK, 256, 0, stream>>>(proj, Hbuf, Lbuf, skip_b,
                                                       dtheta, ctot, actb);
  {  // out_proj -> tmp1 (f32)
    dim3 g(DMODEL / 128, MROWS / 64);
    gemm_bt_kernel<64, 0><<<g, 256, 0, stream>>>(actb, wb_out, tmp1, DINNER, DMODEL, nullptr);
  }
  add_rmsnorm_kernel<<<MROWS, 256, 0, stream>>>(x, tmp1, n2w, x2, h2);
  {  // gate+up fused GLU -> gub (bf16), logical N = 2*DMLP interleaved
    dim3 g(2 * DMLP / 128, MROWS / 128);
    gemm_bt_kernel<128, 2><<<g, 256, 0, stream>>>(h2, wb_gu, gub, DMODEL, DMLP, nullptr);
  }
  {  // down + residual -> out
    dim3 g(DMODEL / 128, MROWS / 64);
    gemm_bt_kernel<64, 0><<<g, 256, 0, stream>>>(gub, wb_d, out, DMLP, DMODEL, x2);
  }
}

// Round 5
// 295.279 us; speedup vs baseline: 1.6770x; 1.1294x over previous
//
#include <hip/hip_runtime.h>

typedef unsigned short u16;
typedef __attribute__((ext_vector_type(8))) short short8;
typedef __attribute__((ext_vector_type(4))) float f32x4;

constexpr int B_N    = 2;
constexpr int SEQ    = 1024;
constexpr int DMODEL = 768;
constexpr int DINNER = 1536;
constexpr int NH     = 24;
constexpr int DMLP   = 1920;
constexpr int NPROJ  = 6936;
constexpr int PP     = 7040;          // padded proj width (55*128)
constexpr int MROWS  = B_N * SEQ;     // 2048
constexpr int NCHUNK = 16;
constexpr int CLEN   = 64;

__device__ __forceinline__ u16 f2bf(float f) {
  union { float f; unsigned u; } x; x.f = f;
  unsigned r = x.u + 0x7fffu + ((x.u >> 16) & 1u);
  return (u16)(r >> 16);
}
__device__ __forceinline__ float bf2f(u16 b) {
  union { unsigned u; float f; } x; x.u = ((unsigned)b) << 16; return x.f;
}

__device__ __forceinline__ void gld_lds16(const u16* g, u16* l) {
  __builtin_amdgcn_global_load_lds((const __attribute__((address_space(1))) void*)g,
                                   (__attribute__((address_space(3))) void*)l, 16, 0, 0);
}

// swizzled bf16 fragment read: 8 consecutive (swizzled) elements at (row, colblock cb)
__device__ __forceinline__ short8 frag(const u16* base, int row, int cb) {
  return *(const short8*)(base + row * 64 + ((cb ^ (row & 7)) << 3));
}
__device__ __forceinline__ int swz_idx(int row, int e) {
  return (((e >> 3) ^ (row & 7)) << 3) | (e & 7);
}

// ---------------- one cast kernel for all weights (f32 -> bf16) -------------
constexpr size_t E0  = (size_t)PP * DMODEL;
constexpr size_t E0s = (size_t)NPROJ * DMODEL;
constexpr size_t E1  = (size_t)DMODEL * DINNER;
constexpr size_t E2  = (size_t)DMLP * DMODEL;
constexpr size_t ETOT = E0 + E1 + 3 * E2;

__global__ void cast_all_kernel(const float* __restrict__ w_in, const float* __restrict__ w_out,
                                const float* __restrict__ w_g, const float* __restrict__ w_u,
                                const float* __restrict__ w_d,
                                u16* __restrict__ wb_in, u16* __restrict__ wb_out,
                                u16* __restrict__ wb_gu, u16* __restrict__ wb_d) {
  size_t i = ((size_t)blockIdx.x * 256 + threadIdx.x) * 4;
  if (i >= ETOT) return;
  float4 v; u16* dst;
  if (i < E0) {
    dst = wb_in + i;
    if (i < E0s) v = *(const float4*)(w_in + i);
    else { v.x = v.y = v.z = v.w = 0.f; }
  } else if (i < E0 + E1) {
    size_t k = i - E0; dst = wb_out + k; v = *(const float4*)(w_out + k);
  } else if (i < E0 + E1 + 2 * E2) {
    // interleaved gate/up: row 2j = gate_j, row 2j+1 = up_j
    size_t k = i - E0 - E1;
    size_t r = k / DMODEL, col = k - r * DMODEL;
    const float* src = (r & 1) ? w_u : w_g;
    v = *(const float4*)(src + (r >> 1) * DMODEL + col);
    dst = wb_gu + k;
  } else {
    size_t k = i - E0 - E1 - 2 * E2; dst = wb_d + k; v = *(const float4*)(w_d + k);
  }
  short4 o;
  o.x = (short)f2bf(v.x); o.y = (short)f2bf(v.y);
  o.z = (short)f2bf(v.z); o.w = (short)f2bf(v.w);
  *(short4*)dst = o;
}

// ---------------- fused (a [+ b]) -> rmsnorm -> bf16 ; optional raw-sum out --
__global__ __launch_bounds__(256) void add_rmsnorm_kernel(
    const float* __restrict__ a, const float* __restrict__ b,
    const float* __restrict__ w, float* __restrict__ sum_out,
    u16* __restrict__ hout) {
  int row = blockIdx.x;
  int t = threadIdx.x;
  const float* pa = a + (size_t)row * DMODEL;
  const float* pb = b ? b + (size_t)row * DMODEL : nullptr;
  float v[3]; float ss = 0.f;
#pragma unroll
  for (int i = 0; i < 3; ++i) {
    int c = t + i * 256;
    float x = pa[c];
    if (pb) x += pb[c];
    v[i] = x; ss += x * x;
  }
#pragma unroll
  for (int o = 32; o > 0; o >>= 1) ss += __shfl_xor(ss, o);
  __shared__ float red[4];
  if ((t & 63) == 0) red[t >> 6] = ss;
  __syncthreads();
  ss = red[0] + red[1] + red[2] + red[3];
  float sc = rsqrtf(ss * (1.f / DMODEL) + 1e-5f);
#pragma unroll
  for (int i = 0; i < 3; ++i) {
    int c = t + i * 256;
    if (sum_out) sum_out[(size_t)row * DMODEL + c] = v[i];
    hout[(size_t)row * DMODEL + c] = f2bf(v[i] * sc * w[c]);
  }
}

// ---------------- bf16 MFMA GEMM: C = A * B^T --------------------------------
// template<BM, BN, MODE>; 4 waves = 2x2, per-wave (BM/2)x(BN/2).
// MODE 0: f32 out (+optional addsrc). MODE 1: bf16 out. MODE 2: glu-paired
// bf16 out (even col = gate, odd col = up -> silu(g)*u at col/2, stride ldc).
template<int BM, int BN, int MODE>
__global__ __launch_bounds__(256) void gemm_bt_kernel(
    const u16* __restrict__ A, const u16* __restrict__ Bw,
    void* __restrict__ Cv, int K, int ldc, const float* __restrict__ addsrc) {
  constexpr int MI = BM / 32;
  constexpr int NJ = BN / 32;
  __shared__ u16 As[BM * 64];
  __shared__ u16 Bs[BN * 64];
  const int t = threadIdx.x;
  const int lane = t & 63;
  const int wave = t >> 6;
  const int wm = wave >> 1, wn = wave & 1;
  const int gx = gridDim.x, gy = gridDim.y;
  const int o = blockIdx.y * gx + blockIdx.x;
  const int nwg = gx * gy;
  const int cid = (o & 7) * (nwg >> 3) + (o >> 3);
  const int bx = cid / gy, by = cid - bx * gy;
  const int m0 = by * BM, n0 = bx * BN;
  f32x4 acc[MI][NJ] = {};
  const int rr = t >> 3;
  const int kc = (t & 7) * 8;
  const u16* ga = A + (size_t)(m0 + rr) * K + kc;
  const u16* gb = Bw + (size_t)(n0 + rr) * K + kc;
  for (int kt = 0; kt < K; kt += 64) {
    __syncthreads();
#pragma unroll
    for (int i = 0; i < MI; ++i)
      gld_lds16(ga + (size_t)i * 32 * K + kt, As + i * 2048 + t * 8);
#pragma unroll
    for (int i = 0; i < NJ; ++i)
      gld_lds16(gb + (size_t)i * 32 * K + kt, Bs + i * 2048 + t * 8);
    __syncthreads();
#pragma unroll
    for (int kh = 0; kh < 2; ++kh) {
      short8 af[MI], bfr[NJ];
#pragma unroll
      for (int i = 0; i < MI; ++i)
        af[i] = *(const short8*)(As + (wm * (BM / 2) + i * 16 + (lane & 15)) * 64 + kh * 32 + (lane >> 4) * 8);
#pragma unroll
      for (int j = 0; j < NJ; ++j)
        bfr[j] = *(const short8*)(Bs + (wn * (BN / 2) + j * 16 + (lane & 15)) * 64 + kh * 32 + (lane >> 4) * 8);
#pragma unroll
      for (int i = 0; i < MI; ++i)
#pragma unroll
        for (int j = 0; j < NJ; ++j)
          acc[i][j] = __builtin_amdgcn_mfma_f32_16x16x32_bf16(af[i], bfr[j], acc[i][j], 0, 0, 0);
    }
  }
  const int cr = (lane >> 4) * 4;
  const int cc = lane & 15;
#pragma unroll
  for (int i = 0; i < MI; ++i) {
#pragma unroll
    for (int j = 0; j < NJ; ++j) {
      int row = m0 + wm * (BM / 2) + i * 16 + cr;
      int col = n0 + wn * (BN / 2) + j * 16 + cc;
      if (MODE == 0) {
        float* C = (float*)Cv;
        float* cp = C + (size_t)row * ldc + col;
        if (addsrc) {
          const float* ap = addsrc + (size_t)row * ldc + col;
#pragma unroll
          for (int r = 0; r < 4; ++r) cp[(size_t)r * ldc] = acc[i][j][r] + ap[(size_t)r * ldc];
        } else {
#pragma unroll
          for (int r = 0; r < 4; ++r) cp[(size_t)r * ldc] = acc[i][j][r];
        }
      } else if (MODE == 1) {
        u16* C = (u16*)Cv;
#pragma unroll
        for (int r = 0; r < 4; ++r)
          C[(size_t)(row + r) * ldc + col] = f2bf(acc[i][j][r]);
      } else {
        u16* C = (u16*)Cv;
#pragma unroll
        for (int r = 0; r < 4; ++r) {
          float v = acc[i][j][r];
          float p = __shfl_xor(v, 1);
          if ((lane & 1) == 0) {
            float g = v, u = p;
            float res = g / (1.f + __expf(-g)) * u;
            C[(size_t)(row + r) * ldc + (col >> 1)] = f2bf(res);
          }
        }
      }
    }
  }
}

// ---------------- prep: B/C rmsnorm+bias (in place, bf16), A=log(alpha),
//                  skip, dtheta, pre-scale x_ssm by gamma. One wave/(m,h). --
__global__ __launch_bounds__(256) void prep_kernel(
    u16* __restrict__ proj, const float* __restrict__ A_log,
    const float* __restrict__ Dv, const float* __restrict__ dt_bias,
    const float* __restrict__ B_bias, const float* __restrict__ C_bias,
    const float* __restrict__ Bnw, const float* __restrict__ Cnw,
    float* __restrict__ Abuf, float* __restrict__ skip_b,
    float* __restrict__ dtheta) {
  int wid = blockIdx.x * 4 + (threadIdx.x >> 6);
  int lane = threadIdx.x & 63;
  int m = wid / NH, h = wid - m * NH;
  u16* row = proj + (size_t)m * PP;

  float Braw = bf2f(row[3072 + h * 64 + lane]);
  float Craw = bf2f(row[4608 + h * 64 + lane]);
  float sb = Braw * Braw, sc2 = Craw * Craw;
#pragma unroll
  for (int o = 32; o > 0; o >>= 1) { sb += __shfl_xor(sb, o); sc2 += __shfl_xor(sc2, o); }
  float rb = rsqrtf(sb * (1.f / 64.f) + 1e-5f);
  float rc = rsqrtf(sc2 * (1.f / 64.f) + 1e-5f);
  row[3072 + h * 64 + lane] = f2bf(Braw * rb * Bnw[lane] + B_bias[h * 64 + lane]);
  row[4608 + h * 64 + lane] = f2bf(Craw * rc * Cnw[lane] + C_bias[h * 64 + lane]);

  float dtr = bf2f(row[6144 + h]) + dt_bias[h];
  float dt = dtr > 20.f ? dtr : log1pf(__expf(dtr));
  float A = -__expf(A_log[h]) * dt;
  float alpha = __expf(A);
  float gamma = (alpha - 1.f) / (A + 1e-6f) * 0.5f + 1.f;

  float xv = bf2f(row[1536 + h * 64 + lane]);
  float sx = xv;
#pragma unroll
  for (int o = 32; o > 0; o >>= 1) sx += __shfl_xor(sx, o);
  row[1536 + h * 64 + lane] = f2bf(xv * gamma);   // pre-scale for scan

  if (lane == 0) {
    Abuf[(size_t)m * NH + h] = A;           // log(alpha)
    skip_b[(size_t)m * NH + h] = Dv[h] * sx;
  }
  if (lane < 32) {
    float th = bf2f(row[6168 + h * 32 + lane]);
    dtheta[(size_t)m * 768 + h * 32 + lane] = dt * th;
  }
}

// ---------------- chunked cumsum of dtheta over s ---------------------------
__global__ __launch_bounds__(256) void cumsum_a_kernel(float* __restrict__ dtheta,
                                                       float* __restrict__ ctot) {
  int bid = blockIdx.x;                  // 96 = 2 * 16 * 3
  int cb = bid % 3, rest = bid / 3;
  int c = rest & 15, b = rest >> 4;
  int col = cb * 256 + threadIdx.x;
  float* p = dtheta + ((size_t)(b * SEQ + c * CLEN)) * 768 + col;
  float acc = 0.f;
#pragma unroll 4
  for (int s = 0; s < CLEN; ++s) {
    acc += p[(size_t)s * 768];
    p[(size_t)s * 768] = acc;
  }
  ctot[((size_t)b * NCHUNK + c) * 768 + col] = acc;
}

__global__ void cumsum_b_kernel(float* __restrict__ ctot) {
  int tid = blockIdx.x * 256 + threadIdx.x;   // < 1536
  int b = tid / 768, col = tid - b * 768;
  float pre = 0.f;
#pragma unroll
  for (int c = 0; c < NCHUNK; ++c) {
    size_t o = ((size_t)b * NCHUNK + c) * 768 + col;
    float v = ctot[o];
    ctot[o] = pre;
    pre += v;
  }
}

// ---------------- rope: rotate B and C pairs in place (bf16) ---------------
__global__ __launch_bounds__(256) void rope_kernel(
    u16* __restrict__ proj, const float* __restrict__ dtheta,
    const float* __restrict__ ctot) {
  int wid = blockIdx.x * 4 + (threadIdx.x >> 6);
  int lane = threadIdx.x & 63;
  int m = wid / NH, h = wid - m * NH;
  int j = lane & 31;
  int b = m >> 10;
  int c = (m >> 6) & 15;
  float ang = dtheta[(size_t)m * 768 + h * 32 + j] +
              ctot[((size_t)b * NCHUNK + c) * 768 + h * 32 + j];
  float sn, cs;
  __sincosf(ang, &sn, &cs);
  int base = (lane < 32) ? 3072 : 4608;
  unsigned* p = (unsigned*)(proj + (size_t)m * PP + base + h * 64) + j;
  unsigned v = *p;
  float x1 = bf2f((u16)(v & 0xffffu));
  float x2 = bf2f((u16)(v >> 16));
  *p = (unsigned)f2bf(cs * x1 - sn * x2) | ((unsigned)f2bf(sn * x1 + cs * x2) << 16);
}

// ---------------- kernel A: H_out[p][n] = sum_t ratio[t] * xs[t,p] * B[t,n] --
__global__ __launch_bounds__(256) void houtA_kernel(
    const u16* __restrict__ proj, const float* __restrict__ Abuf,
    float* __restrict__ Lbuf, float* __restrict__ Hbuf) {
  int c = blockIdx.x & 15, bh = blockIdx.x >> 4;
  int b = bh / NH, h = bh - b * NH;
  int t = threadIdx.x, w = t >> 6, l = t & 63;
  __shared__ float sTmp[64][65];
  __shared__ u16 sBT[64 * 64];
  __shared__ u16 sXT[64 * 64];
  __shared__ float sRatio[64];
  int m0 = b * SEQ + c * CLEN;
  if (w == 0) {
    float v = Abuf[(size_t)(m0 + l) * NH + h];
#pragma unroll
    for (int o = 1; o < 64; o <<= 1) {
      float u = __shfl_up(v, o);
      if (l >= o) v += u;
    }
    Lbuf[(size_t)(m0 + l) * NH + h] = v;
    float L63 = __shfl(v, 63);
    sRatio[l] = __expf(L63 - v);
  }
  int rr = t >> 2, q = t & 3;
  {  // stage rope'd B (already rotated) -> sTmp (f32)
    const u16* row = proj + (size_t)(m0 + rr) * PP + 3072 + h * 64;
#pragma unroll
    for (int k = 0; k < 4; ++k) {
      int e = q * 16 + k * 4;
      short4 sv = *(const short4*)(row + e);
      float4 ov;
      ov.x = bf2f((u16)sv.x); ov.y = bf2f((u16)sv.y);
      ov.z = bf2f((u16)sv.z); ov.w = bf2f((u16)sv.w);
      *(float4*)&sTmp[rr][e] = ov;
    }
  }
  __syncthreads();
  {  // transpose -> sBT[n][t] bf16, rotation + swizzle
#pragma unroll
    for (int k = 0; k < 8; ++k) {
      int tw = (l + w * 8 + k) & 31;
      int t0 = tw * 2;
      unsigned pk = (unsigned)f2bf(sTmp[t0][l]) | ((unsigned)f2bf(sTmp[t0 + 1][l]) << 16);
      *(unsigned*)(sBT + l * 64 + swz_idx(l, t0)) = pk;
    }
  }
  __syncthreads();
  {  // stage xs -> sTmp
    const u16* row = proj + (size_t)(m0 + rr) * PP + 1536 + h * 64;
#pragma unroll
    for (int k = 0; k < 4; ++k) {
      int e = q * 16 + k * 4;
      short4 sv = *(const short4*)(row + e);
      float4 ov;
      ov.x = bf2f((u16)sv.x); ov.y = bf2f((u16)sv.y);
      ov.z = bf2f((u16)sv.z); ov.w = bf2f((u16)sv.w);
      *(float4*)&sTmp[rr][e] = ov;
    }
  }
  __syncthreads();
  {  // transpose + ratio-scale -> sXT[p][t]
#pragma unroll
    for (int k = 0; k < 8; ++k) {
      int tw = (l + w * 8 + k) & 31;
      int t0 = tw * 2;
      float v0 = sTmp[t0][l] * sRatio[t0];
      float v1 = sTmp[t0 + 1][l] * sRatio[t0 + 1];
      unsigned pk = (unsigned)f2bf(v0) | ((unsigned)f2bf(v1) << 16);
      *(unsigned*)(sXT + l * 64 + swz_idx(l, t0)) = pk;
    }
  }
  __syncthreads();
  f32x4 acc[4] = {};
#pragma unroll
  for (int kh = 0; kh < 2; ++kh) {
    int cb = kh * 4 + (l >> 4);
    short8 af = frag(sXT, w * 16 + (l & 15), cb);
#pragma unroll
    for (int j = 0; j < 4; ++j)
      acc[j] = __builtin_amdgcn_mfma_f32_16x16x32_bf16(af, frag(sBT, j * 16 + (l & 15), cb), acc[j], 0, 0, 0);
  }
  float* Hp = Hbuf + ((size_t)(bh * NCHUNK + c)) * 4096;
  int pr = w * 16 + ((l >> 4) << 2);
#pragma unroll
  for (int j = 0; j < 4; ++j)
#pragma unroll
    for (int r = 0; r < 4; ++r)
      Hp[(size_t)(pr + r) * 64 + j * 16 + (l & 15)] = acc[j][r];
}

// ---------------- scan phase 2: element-parallel chunk recurrence ----------
// grid = 48*16 blocks; thread owns one of 4096 state elements per (b,h).
__global__ __launch_bounds__(256) void scan2_kernel(
    float* __restrict__ Hbuf, const float* __restrict__ Lbuf) {
  int bh = blockIdx.x >> 4;
  int e = (blockIdx.x & 15) * 256 + threadIdx.x;
  int b = bh / NH, h = bh - b * NH;
  float S = 0.f;
  for (int c = 0; c < NCHUNK; ++c) {
    float* Hp = Hbuf + ((size_t)(bh * NCHUNK + c)) * 4096 + e;
    float P = __expf(Lbuf[(size_t)(b * SEQ + c * CLEN + CLEN - 1) * NH + h]);
    float v = *Hp;
    *Hp = S;
    S = P * S + v;
  }
}

// ---------------- kernel B: G=C.B^T, mask, Y = Gm@xs + e^L (C@Hin^T),
//                  + skip, * silu(z) -> actb (bf16). ------------------------
__global__ __launch_bounds__(256) void intraB_kernel(
    const u16* __restrict__ proj, const float* __restrict__ Hbuf,
    const float* __restrict__ Lbuf, const float* __restrict__ skip_b,
    u16* __restrict__ actb) {
  int c = blockIdx.x & 15, bh = blockIdx.x >> 4;
  int b = bh / NH, h = bh - b * NH;
  int t = threadIdx.x, w = t >> 6, l = t & 63;
  __shared__ u16 sC[64 * 64];
  __shared__ u16 sBH[64 * 64];
  __shared__ u16 sXT[64 * 64];
  __shared__ union UU { float tmp[64][65]; u16 gm[64 * 64]; } uS;
  __shared__ float sL[64], sSkip[64];
  int m0 = b * SEQ + c * CLEN;
  if (w == 0) {
    sL[l] = Lbuf[(size_t)(m0 + l) * NH + h];
    sSkip[l] = skip_b[(size_t)(m0 + l) * NH + h];
  }
  int rr = t >> 2, q = t & 3;
  {  // stage rope'd C -> sC (bf16 swizzled), rope'd B -> sBH, xs -> uS.tmp
    const u16* rowC = proj + (size_t)(m0 + rr) * PP + 4608 + h * 64;
    const u16* rowB = proj + (size_t)(m0 + rr) * PP + 3072 + h * 64;
    const u16* rowX = proj + (size_t)(m0 + rr) * PP + 1536 + h * 64;
#pragma unroll
    for (int k = 0; k < 4; ++k) {
      int e = q * 16 + k * 4;
      int idx = swz_idx(rr, e);
      short4 cv = *(const short4*)(rowC + e);
      *(unsigned*)(sC + rr * 64 + idx)     = (unsigned)(u16)cv.x | ((unsigned)(u16)cv.y << 16);
      *(unsigned*)(sC + rr * 64 + idx + 2) = (unsigned)(u16)cv.z | ((unsigned)(u16)cv.w << 16);
      short4 bv = *(const short4*)(rowB + e);
      *(unsigned*)(sBH + rr * 64 + idx)     = (unsigned)(u16)bv.x | ((unsigned)(u16)bv.y << 16);
      *(unsigned*)(sBH + rr * 64 + idx + 2) = (unsigned)(u16)bv.z | ((unsigned)(u16)bv.w << 16);
      short4 xv = *(const short4*)(rowX + e);
      float4 ov;
      ov.x = bf2f((u16)xv.x); ov.y = bf2f((u16)xv.y);
      ov.z = bf2f((u16)xv.z); ov.w = bf2f((u16)xv.w);
      *(float4*)&uS.tmp[rr][e] = ov;
    }
  }
  __syncthreads();
  {  // build sXT (transpose of xs)
#pragma unroll
    for (int k = 0; k < 8; ++k) {
      int tw = (l + w * 8 + k) & 31;
      int t0 = tw * 2;
      unsigned pk = (unsigned)f2bf(uS.tmp[t0][l]) | ((unsigned)f2bf(uS.tmp[t0 + 1][l]) << 16);
      *(unsigned*)(sXT + l * 64 + swz_idx(l, t0)) = pk;
    }
  }
  __syncthreads();
  // G = C . B^T  (k = n)
  f32x4 g4[4] = {};
#pragma unroll
  for (int kh = 0; kh < 2; ++kh) {
    int cb = kh * 4 + (l >> 4);
    short8 af = frag(sC, w * 16 + (l & 15), cb);
#pragma unroll
    for (int j = 0; j < 4; ++j)
      g4[j] = __builtin_amdgcn_mfma_f32_16x16x32_bf16(af, frag(sBH, j * 16 + (l & 15), cb), g4[j], 0, 0, 0);
  }
  __syncthreads();
  {  // mask + decay -> uS.gm ; stage H_in -> sBH
    int sr = w * 16 + ((l >> 4) << 2);
#pragma unroll
    for (int j = 0; j < 4; ++j) {
      int tc = j * 16 + (l & 15);
#pragma unroll
      for (int r = 0; r < 4; ++r) {
        int s = sr + r;
        float gv = (tc <= s) ? g4[j][r] * __expf(sL[s] - sL[tc]) : 0.f;
        uS.gm[s * 64 + swz_idx(s, tc)] = f2bf(gv);
      }
    }
    const float* Hp = Hbuf + ((size_t)(bh * NCHUNK + c)) * 4096 + rr * 64;
#pragma unroll
    for (int k = 0; k < 4; ++k) {
      int e = q * 16 + k * 4;
      float4 v = *(const float4*)(Hp + e);
      unsigned lo = (unsigned)f2bf(v.x) | ((unsigned)f2bf(v.y) << 16);
      unsigned hi = (unsigned)f2bf(v.z) | ((unsigned)f2bf(v.w) << 16);
      int idx = swz_idx(rr, e);
      *(unsigned*)(sBH + rr * 64 + idx) = lo;
      *(unsigned*)(sBH + rr * 64 + idx + 2) = hi;
    }
  }
  __syncthreads();
  // Y1 = Gm @ xs (k = t), Y2 = C @ Hin^T (k = n)
  f32x4 y1[4] = {}, y2[4] = {};
#pragma unroll
  for (int kh = 0; kh < 2; ++kh) {
    int cb = kh * 4 + (l >> 4);
    short8 ag = frag(uS.gm, w * 16 + (l & 15), cb);
    short8 ac = frag(sC, w * 16 + (l & 15), cb);
#pragma unroll
    for (int j = 0; j < 4; ++j) {
      y1[j] = __builtin_amdgcn_mfma_f32_16x16x32_bf16(ag, frag(sXT, j * 16 + (l & 15), cb), y1[j], 0, 0, 0);
      y2[j] = __builtin_amdgcn_mfma_f32_16x16x32_bf16(ac, frag(sBH, j * 16 + (l & 15), cb), y2[j], 0, 0, 0);
    }
  }
  // epilogue: y + skip, * silu(z) -> actb
  int sr = w * 16 + ((l >> 4) << 2);
#pragma unroll
  for (int r = 0; r < 4; ++r) {
    int s = sr + r;
    float scale = __expf(sL[s]);
    float skp = sSkip[s];
    size_t mrow = (size_t)(m0 + s);
#pragma unroll
    for (int j = 0; j < 4; ++j) {
      int p = j * 16 + (l & 15);
      float y = y1[j][r] + scale * y2[j][r] + skp;
      float z = bf2f(proj[mrow * PP + h * 64 + p]);
      float sg = 1.f / (1.f + __expf(-z));
      actb[mrow * DINNER + h * 64 + p] = f2bf(y * z * sg);
    }
  }
}

extern "C" void kernel_launch(void* const* d_in, const int* in_sizes, int n_in,
                              void* d_out, int out_size, void* d_ws, size_t ws_size,
                              hipStream_t stream) {
  (void)in_sizes; (void)n_in; (void)out_size; (void)ws_size;
  const float* x      = (const float*)d_in[0];
  const float* n1w    = (const float*)d_in[1];
  const float* n2w    = (const float*)d_in[2];
  const float* w_in   = (const float*)d_in[3];
  const float* w_out  = (const float*)d_in[4];
  const float* A_log  = (const float*)d_in[5];
  const float* Dv     = (const float*)d_in[6];
  const float* dt_b   = (const float*)d_in[7];
  const float* B_bias = (const float*)d_in[8];
  const float* C_bias = (const float*)d_in[9];
  const float* Bnw    = (const float*)d_in[10];
  const float* Cnw    = (const float*)d_in[11];
  const float* w_g    = (const float*)d_in[12];
  const float* w_u    = (const float*)d_in[13];
  const float* w_d    = (const float*)d_in[14];
  float* out = (float*)d_out;

  char* ws = (char*)d_ws;
  size_t off = 0;
  auto alloc = [&](size_t bytes) -> char* {
    char* p = ws + off;
    off = (off + bytes + 255) & ~(size_t)255;
    return p;
  };
  u16*   wb_in  = (u16*)  alloc(E0 * 2);
  u16*   wb_out = (u16*)  alloc(E1 * 2);
  u16*   wb_gu  = (u16*)  alloc(E2 * 2 * 2);      // interleaved gate/up rows
  u16*   wb_d   = (u16*)  alloc(E2 * 2);
  u16*   h1     = (u16*)  alloc((size_t)MROWS * DMODEL * 2);
  u16*   proj   = (u16*)  alloc((size_t)MROWS * PP * 2);
  float* Abuf   = (float*)alloc((size_t)MROWS * NH * 4);
  float* skip_b = (float*)alloc((size_t)MROWS * NH * 4);
  float* Lbuf   = (float*)alloc((size_t)MROWS * NH * 4);
  float* dtheta = (float*)alloc((size_t)MROWS * 768 * 4);
  float* ctot   = (float*)alloc((size_t)B_N * NCHUNK * 768 * 4);
  float* Hbuf   = (float*)alloc((size_t)B_N * NH * NCHUNK * 4096 * 4);
  u16*   actb   = (u16*)  alloc((size_t)MROWS * DINNER * 2);
  float* tmp1   = (float*)alloc((size_t)MROWS * DMODEL * 4);
  float* x2     = (float*)alloc((size_t)MROWS * DMODEL * 4);
  u16*   h2     = (u16*)  alloc((size_t)MROWS * DMODEL * 2);
  u16*   gub    = (u16*)  alloc((size_t)MROWS * DMLP * 2);

  cast_all_kernel<<<(int)((ETOT / 4 + 255) / 256), 256, 0, stream>>>(
      w_in, w_out, w_g, w_u, w_d, wb_in, wb_out, wb_gu, wb_d);
  add_rmsnorm_kernel<<<MROWS, 256, 0, stream>>>(x, nullptr, n1w, nullptr, h1);
  {  // in_proj -> proj (bf16): 55 x 32 = 1760 blocks
    dim3 g(PP / 128, MROWS / 64);
    gemm_bt_kernel<64, 128, 1><<<g, 256, 0, stream>>>(h1, wb_in, proj, DMODEL, PP, nullptr);
  }
  prep_kernel<<<MROWS * NH / 4, 256, 0, stream>>>(proj, A_log, Dv, dt_b, B_bias, C_bias,
                                                  Bnw, Cnw, Abuf, skip_b, dtheta);
  cumsum_a_kernel<<<B_N * NCHUNK * 3, 256, 0, stream>>>(dtheta, ctot);
  cumsum_b_kernel<<<6, 256, 0, stream>>>(ctot);
  rope_kernel<<<MROWS * NH / 4, 256, 0, stream>>>(proj, dtheta, ctot);
  houtA_kernel<<<B_N * NH * NCHUNK, 256, 0, stream>>>(proj, Abuf, Lbuf, Hbuf);
  scan2_kernel<<<B_N * NH * NCHUNK, 256, 0, stream>>>(Hbuf, Lbuf);
  intraB_kernel<<<B_N * NH * NCHUNK, 256, 0, stream>>>(proj, Hbuf, Lbuf, skip_b, actb);
  {  // out_proj -> tmp1 (f32): 12 x 32 = 384 blocks
    dim3 g(DMODEL / 64, MROWS / 64);
    gemm_bt_kernel<64, 64, 0><<<g, 256, 0, stream>>>(actb, wb_out, tmp1, DINNER, DMODEL, nullptr);
  }
  add_rmsnorm_kernel<<<MROWS, 256, 0, stream>>>(x, tmp1, n2w, x2, h2);
  {  // gate+up fused GLU -> gub (bf16): 30 x 32 = 960 blocks
    dim3 g(2 * DMLP / 128, MROWS / 64);
    gemm_bt_kernel<64, 128, 2><<<g, 256, 0, stream>>>(h2, wb_gu, gub, DMODEL, DMLP, nullptr);
  }
  {  // down + residual -> out: 12 x 32 = 384 blocks
    dim3 g(DMODEL / 64, MROWS / 64);
    gemm_bt_kernel<64, 64, 0><<<g, 256, 0, stream>>>(gub, wb_d, out, DMLP, DMODEL, x2);
  }
}

// Round 6
// 283.043 us; speedup vs baseline: 1.7495x; 1.0432x over previous
//
#include <hip/hip_runtime.h>

typedef unsigned short u16;
typedef __attribute__((ext_vector_type(8))) short short8;
typedef __attribute__((ext_vector_type(4))) float f32x4;

constexpr int B_N    = 2;
constexpr int SEQ    = 1024;
constexpr int DMODEL = 768;
constexpr int DINNER = 1536;
constexpr int NH     = 24;
constexpr int DMLP   = 1920;
constexpr int NPROJ  = 6936;
constexpr int PP     = 7040;          // padded proj width (55*128)
constexpr int MROWS  = B_N * SEQ;     // 2048
constexpr int NCHUNK = 16;
constexpr int CLEN   = 64;

__device__ __forceinline__ u16 f2bf(float f) {
  union { float f; unsigned u; } x; x.f = f;
  unsigned r = x.u + 0x7fffu + ((x.u >> 16) & 1u);
  return (u16)(r >> 16);
}
__device__ __forceinline__ float bf2f(u16 b) {
  union { unsigned u; float f; } x; x.u = ((unsigned)b) << 16; return x.f;
}

__device__ __forceinline__ void gld_lds16(const u16* g, u16* l) {
  __builtin_amdgcn_global_load_lds((const __attribute__((address_space(1))) void*)g,
                                   (__attribute__((address_space(3))) void*)l, 16, 0, 0);
}

// swizzled bf16 fragment read: chunk cb (8 elems) of row, XOR-swizzled
__device__ __forceinline__ short8 frag(const u16* base, int row, int cb) {
  return *(const short8*)(base + row * 64 + ((cb ^ (row & 7)) << 3));
}
__device__ __forceinline__ int swz_idx(int row, int e) {
  return (((e >> 3) ^ (row & 7)) << 3) | (e & 7);
}

// ---------------- one cast kernel for all weights (f32 -> bf16) -------------
constexpr size_t E0  = (size_t)PP * DMODEL;
constexpr size_t E0s = (size_t)NPROJ * DMODEL;
constexpr size_t E1  = (size_t)DMODEL * DINNER;
constexpr size_t E2  = (size_t)DMLP * DMODEL;
constexpr size_t ETOT = E0 + E1 + 3 * E2;

__global__ void cast_all_kernel(const float* __restrict__ w_in, const float* __restrict__ w_out,
                                const float* __restrict__ w_g, const float* __restrict__ w_u,
                                const float* __restrict__ w_d,
                                u16* __restrict__ wb_in, u16* __restrict__ wb_out,
                                u16* __restrict__ wb_gu, u16* __restrict__ wb_d) {
  size_t i = ((size_t)blockIdx.x * 256 + threadIdx.x) * 4;
  if (i >= ETOT) return;
  float4 v; u16* dst;
  if (i < E0) {
    dst = wb_in + i;
    if (i < E0s) v = *(const float4*)(w_in + i);
    else { v.x = v.y = v.z = v.w = 0.f; }
  } else if (i < E0 + E1) {
    size_t k = i - E0; dst = wb_out + k; v = *(const float4*)(w_out + k);
  } else if (i < E0 + E1 + 2 * E2) {
    // interleaved gate/up: row 2j = gate_j, row 2j+1 = up_j
    size_t k = i - E0 - E1;
    size_t r = k / DMODEL, col = k - r * DMODEL;
    const float* src = (r & 1) ? w_u : w_g;
    v = *(const float4*)(src + (r >> 1) * DMODEL + col);
    dst = wb_gu + k;
  } else {
    size_t k = i - E0 - E1 - 2 * E2; dst = wb_d + k; v = *(const float4*)(w_d + k);
  }
  short4 o;
  o.x = (short)f2bf(v.x); o.y = (short)f2bf(v.y);
  o.z = (short)f2bf(v.z); o.w = (short)f2bf(v.w);
  *(short4*)dst = o;
}

// ---------------- fused (a [+ b]) -> rmsnorm -> bf16 ; optional raw-sum out --
__global__ __launch_bounds__(256) void add_rmsnorm_kernel(
    const float* __restrict__ a, const float* __restrict__ b,
    const float* __restrict__ w, float* __restrict__ sum_out,
    u16* __restrict__ hout) {
  int row = blockIdx.x;
  int t = threadIdx.x;
  const float* pa = a + (size_t)row * DMODEL;
  const float* pb = b ? b + (size_t)row * DMODEL : nullptr;
  float v[3]; float ss = 0.f;
#pragma unroll
  for (int i = 0; i < 3; ++i) {
    int c = t + i * 256;
    float x = pa[c];
    if (pb) x += pb[c];
    v[i] = x; ss += x * x;
  }
#pragma unroll
  for (int o = 32; o > 0; o >>= 1) ss += __shfl_xor(ss, o);
  __shared__ float red[4];
  if ((t & 63) == 0) red[t >> 6] = ss;
  __syncthreads();
  ss = red[0] + red[1] + red[2] + red[3];
  float sc = rsqrtf(ss * (1.f / DMODEL) + 1e-5f);
#pragma unroll
  for (int i = 0; i < 3; ++i) {
    int c = t + i * 256;
    if (sum_out) sum_out[(size_t)row * DMODEL + c] = v[i];
    hout[(size_t)row * DMODEL + c] = f2bf(v[i] * sc * w[c]);
  }
}

// ---------------- bf16 MFMA GEMM: C = A * B^T --------------------------------
// template<BM, BN, MODE>; 4 waves = 2x2. T2 swizzle: pre-swizzled global
// source (rule #21) + linear LDS dest + swizzled fragment read.
// MODE 0: f32 out (+optional addsrc). MODE 1: bf16 out. MODE 2: glu-paired.
template<int BM, int BN, int MODE>
__global__ __launch_bounds__(256) void gemm_bt_kernel(
    const u16* __restrict__ A, const u16* __restrict__ Bw,
    void* __restrict__ Cv, int K, int ldc, const float* __restrict__ addsrc) {
  constexpr int MI = BM / 32;
  constexpr int NJ = BN / 32;
  __shared__ u16 As[BM * 64];
  __shared__ u16 Bs[BN * 64];
  const int t = threadIdx.x;
  const int lane = t & 63;
  const int wave = t >> 6;
  const int wm = wave >> 1, wn = wave & 1;
  const int gx = gridDim.x, gy = gridDim.y;
  const int o = blockIdx.y * gx + blockIdx.x;
  const int nwg = gx * gy;
  const int cid = (o & 7) * (nwg >> 3) + (o >> 3);
  const int bx = cid / gy, by = cid - bx * gy;
  const int m0 = by * BM, n0 = bx * BN;
  f32x4 acc[MI][NJ] = {};
  const int rr = t >> 3;
  const int kc = (((t & 7) ^ (rr & 7))) * 8;     // inverse-swizzled source chunk
  const u16* ga = A + (size_t)(m0 + rr) * K + kc;
  const u16* gb = Bw + (size_t)(n0 + rr) * K + kc;
  for (int kt = 0; kt < K; kt += 64) {
    __syncthreads();
#pragma unroll
    for (int i = 0; i < MI; ++i)
      gld_lds16(ga + (size_t)i * 32 * K + kt, As + i * 2048 + t * 8);
#pragma unroll
    for (int i = 0; i < NJ; ++i)
      gld_lds16(gb + (size_t)i * 32 * K + kt, Bs + i * 2048 + t * 8);
    __syncthreads();
#pragma unroll
    for (int kh = 0; kh < 2; ++kh) {
      const int cq = kh * 4 + (lane >> 4);
      short8 af[MI], bfr[NJ];
#pragma unroll
      for (int i = 0; i < MI; ++i)
        af[i] = frag(As, wm * (BM / 2) + i * 16 + (lane & 15), cq);
#pragma unroll
      for (int j = 0; j < NJ; ++j)
        bfr[j] = frag(Bs, wn * (BN / 2) + j * 16 + (lane & 15), cq);
#pragma unroll
      for (int i = 0; i < MI; ++i)
#pragma unroll
        for (int j = 0; j < NJ; ++j)
          acc[i][j] = __builtin_amdgcn_mfma_f32_16x16x32_bf16(af[i], bfr[j], acc[i][j], 0, 0, 0);
    }
  }
  const int cr = (lane >> 4) * 4;
  const int cc = lane & 15;
#pragma unroll
  for (int i = 0; i < MI; ++i) {
#pragma unroll
    for (int j = 0; j < NJ; ++j) {
      int row = m0 + wm * (BM / 2) + i * 16 + cr;
      int col = n0 + wn * (BN / 2) + j * 16 + cc;
      if (MODE == 0) {
        float* C = (float*)Cv;
        float* cp = C + (size_t)row * ldc + col;
        if (addsrc) {
          const float* ap = addsrc + (size_t)row * ldc + col;
#pragma unroll
          for (int r = 0; r < 4; ++r) cp[(size_t)r * ldc] = acc[i][j][r] + ap[(size_t)r * ldc];
        } else {
#pragma unroll
          for (int r = 0; r < 4; ++r) cp[(size_t)r * ldc] = acc[i][j][r];
        }
      } else if (MODE == 1) {
        u16* C = (u16*)Cv;
#pragma unroll
        for (int r = 0; r < 4; ++r)
          C[(size_t)(row + r) * ldc + col] = f2bf(acc[i][j][r]);
      } else {
        u16* C = (u16*)Cv;
#pragma unroll
        for (int r = 0; r < 4; ++r) {
          float v = acc[i][j][r];
          float p = __shfl_xor(v, 1);
          if ((lane & 1) == 0) {
            float g = v, u = p;
            float res = g / (1.f + __expf(-g)) * u;
            C[(size_t)(row + r) * ldc + (col >> 1)] = f2bf(res);
          }
        }
      }
    }
  }
}

// ---------------- prep: B/C rmsnorm+bias (in place, bf16), A=log(alpha),
//                  skip, dtheta, pre-scale x_ssm by gamma. One wave/(m,h). --
__global__ __launch_bounds__(256) void prep_kernel(
    u16* __restrict__ proj, const float* __restrict__ A_log,
    const float* __restrict__ Dv, const float* __restrict__ dt_bias,
    const float* __restrict__ B_bias, const float* __restrict__ C_bias,
    const float* __restrict__ Bnw, const float* __restrict__ Cnw,
    float* __restrict__ Abuf, float* __restrict__ skip_b,
    float* __restrict__ dtheta) {
  int wid = blockIdx.x * 4 + (threadIdx.x >> 6);
  int lane = threadIdx.x & 63;
  int m = wid / NH, h = wid - m * NH;
  u16* row = proj + (size_t)m * PP;

  float Braw = bf2f(row[3072 + h * 64 + lane]);
  float Craw = bf2f(row[4608 + h * 64 + lane]);
  float sb = Braw * Braw, sc2 = Craw * Craw;
#pragma unroll
  for (int o = 32; o > 0; o >>= 1) { sb += __shfl_xor(sb, o); sc2 += __shfl_xor(sc2, o); }
  float rb = rsqrtf(sb * (1.f / 64.f) + 1e-5f);
  float rc = rsqrtf(sc2 * (1.f / 64.f) + 1e-5f);
  row[3072 + h * 64 + lane] = f2bf(Braw * rb * Bnw[lane] + B_bias[h * 64 + lane]);
  row[4608 + h * 64 + lane] = f2bf(Craw * rc * Cnw[lane] + C_bias[h * 64 + lane]);

  float dtr = bf2f(row[6144 + h]) + dt_bias[h];
  float dt = dtr > 20.f ? dtr : log1pf(__expf(dtr));
  float A = -__expf(A_log[h]) * dt;
  float alpha = __expf(A);
  float gamma = (alpha - 1.f) / (A + 1e-6f) * 0.5f + 1.f;

  float xv = bf2f(row[1536 + h * 64 + lane]);
  float sx = xv;
#pragma unroll
  for (int o = 32; o > 0; o >>= 1) sx += __shfl_xor(sx, o);
  row[1536 + h * 64 + lane] = f2bf(xv * gamma);   // pre-scale for scan

  if (lane == 0) {
    Abuf[(size_t)m * NH + h] = A;           // log(alpha)
    skip_b[(size_t)m * NH + h] = Dv[h] * sx;
  }
  if (lane < 32) {
    float th = bf2f(row[6168 + h * 32 + lane]);
    dtheta[(size_t)m * 768 + h * 32 + lane] = dt * th;
  }
}

// ---------------- chunked cumsum of dtheta over s ---------------------------
__global__ __launch_bounds__(256) void cumsum_a_kernel(float* __restrict__ dtheta,
                                                       float* __restrict__ ctot) {
  int bid = blockIdx.x;                  // 96 = 2 * 16 * 3
  int cb = bid % 3, rest = bid / 3;
  int c = rest & 15, b = rest >> 4;
  int col = cb * 256 + threadIdx.x;
  float* p = dtheta + ((size_t)(b * SEQ + c * CLEN)) * 768 + col;
  float acc = 0.f;
#pragma unroll 4
  for (int s = 0; s < CLEN; ++s) {
    acc += p[(size_t)s * 768];
    p[(size_t)s * 768] = acc;
  }
  ctot[((size_t)b * NCHUNK + c) * 768 + col] = acc;
}

__global__ void cumsum_b_kernel(float* __restrict__ ctot) {
  int tid = blockIdx.x * 256 + threadIdx.x;   // < 1536
  int b = tid / 768, col = tid - b * 768;
  float pre = 0.f;
#pragma unroll
  for (int c = 0; c < NCHUNK; ++c) {
    size_t o = ((size_t)b * NCHUNK + c) * 768 + col;
    float v = ctot[o];
    ctot[o] = pre;
    pre += v;
  }
}

// ---------------- rope: rotate B and C pairs in place (bf16) ---------------
__global__ __launch_bounds__(256) void rope_kernel(
    u16* __restrict__ proj, const float* __restrict__ dtheta,
    const float* __restrict__ ctot) {
  int wid = blockIdx.x * 4 + (threadIdx.x >> 6);
  int lane = threadIdx.x & 63;
  int m = wid / NH, h = wid - m * NH;
  int j = lane & 31;
  int b = m >> 10;
  int c = (m >> 6) & 15;
  float ang = dtheta[(size_t)m * 768 + h * 32 + j] +
              ctot[((size_t)b * NCHUNK + c) * 768 + h * 32 + j];
  float sn, cs;
  __sincosf(ang, &sn, &cs);
  int base = (lane < 32) ? 3072 : 4608;
  unsigned* p = (unsigned*)(proj + (size_t)m * PP + base + h * 64) + j;
  unsigned v = *p;
  float x1 = bf2f((u16)(v & 0xffffu));
  float x2 = bf2f((u16)(v >> 16));
  *p = (unsigned)f2bf(cs * x1 - sn * x2) | ((unsigned)f2bf(sn * x1 + cs * x2) << 16);
}

// ---------------- scan kernel A: per (bh, chunk):
//   L prefix; G = C.B^T (direct-global frags); Gm = mask/decay(G);
//   Y1 = Gm @ xs ; H_out = xs^T . (ratio*B). Writes Lbuf, Hbuf, y1b. --------
__global__ __launch_bounds__(256) void scanA_kernel(
    const u16* __restrict__ proj, const float* __restrict__ Abuf,
    float* __restrict__ Lbuf, float* __restrict__ Hbuf,
    float* __restrict__ y1b) {
  int c = blockIdx.x & 15, bh = blockIdx.x >> 4;
  int b = bh / NH, h = bh - b * NH;
  int t = threadIdx.x, w = t >> 6, l = t & 63;
  __shared__ float sTmp[64][65];
  __shared__ u16 sBT[64 * 64];   // (ratio*B)^T : [n][t]
  __shared__ u16 sXT[64 * 64];   // xs^T : [p][t]
  __shared__ u16 sGm[64 * 64];   // masked decayed G : [s][t]
  __shared__ float sRatio[64], sL[64];
  int m0 = b * SEQ + c * CLEN;
  if (w == 0) {
    float v = Abuf[(size_t)(m0 + l) * NH + h];
#pragma unroll
    for (int o = 1; o < 64; o <<= 1) {
      float u = __shfl_up(v, o);
      if (l >= o) v += u;
    }
    Lbuf[(size_t)(m0 + l) * NH + h] = v;
    sL[l] = v;
    float L63 = __shfl(v, 63);
    sRatio[l] = __expf(L63 - v);
  }
  int rr = t >> 2, q = t & 3;
  {  // stage rope'd B -> sTmp (f32)
    const u16* row = proj + (size_t)(m0 + rr) * PP + 3072 + h * 64;
#pragma unroll
    for (int k = 0; k < 4; ++k) {
      int e = q * 16 + k * 4;
      short4 sv = *(const short4*)(row + e);
      float4 ov;
      ov.x = bf2f((u16)sv.x); ov.y = bf2f((u16)sv.y);
      ov.z = bf2f((u16)sv.z); ov.w = bf2f((u16)sv.w);
      *(float4*)&sTmp[rr][e] = ov;
    }
  }
  // direct-global fragment loads for G = C . B^T
  const u16* baseC = proj + (size_t)m0 * PP + 4608 + h * 64;
  const u16* baseB = proj + (size_t)m0 * PP + 3072 + h * 64;
  short8 cf[2], bgf[2][4];
#pragma unroll
  for (int kh = 0; kh < 2; ++kh) {
    int cq = kh * 4 + (l >> 4);
    cf[kh] = *(const short8*)(baseC + (size_t)(w * 16 + (l & 15)) * PP + cq * 8);
#pragma unroll
    for (int j = 0; j < 4; ++j)
      bgf[kh][j] = *(const short8*)(baseB + (size_t)(j * 16 + (l & 15)) * PP + cq * 8);
  }
  __syncthreads();          // sTmp(B), sRatio, sL ready
  f32x4 g4[4] = {};
#pragma unroll
  for (int kh = 0; kh < 2; ++kh)
#pragma unroll
    for (int j = 0; j < 4; ++j)
      g4[j] = __builtin_amdgcn_mfma_f32_16x16x32_bf16(cf[kh], bgf[kh][j], g4[j], 0, 0, 0);
  {  // transpose + ratio-scale -> sBT[n][t]
#pragma unroll
    for (int k = 0; k < 8; ++k) {
      int tw = (l + w * 8 + k) & 31;
      int t0 = tw * 2;
      float v0 = sTmp[t0][l] * sRatio[t0];
      float v1 = sTmp[t0 + 1][l] * sRatio[t0 + 1];
      unsigned pk = (unsigned)f2bf(v0) | ((unsigned)f2bf(v1) << 16);
      *(unsigned*)(sBT + l * 64 + swz_idx(l, t0)) = pk;
    }
  }
  __syncthreads();          // sTmp consumed
  {  // stage xs -> sTmp
    const u16* row = proj + (size_t)(m0 + rr) * PP + 1536 + h * 64;
#pragma unroll
    for (int k = 0; k < 4; ++k) {
      int e = q * 16 + k * 4;
      short4 sv = *(const short4*)(row + e);
      float4 ov;
      ov.x = bf2f((u16)sv.x); ov.y = bf2f((u16)sv.y);
      ov.z = bf2f((u16)sv.z); ov.w = bf2f((u16)sv.w);
      *(float4*)&sTmp[rr][e] = ov;
    }
  }
  __syncthreads();
  {  // transpose -> sXT[p][t] (raw)
#pragma unroll
    for (int k = 0; k < 8; ++k) {
      int tw = (l + w * 8 + k) & 31;
      int t0 = tw * 2;
      unsigned pk = (unsigned)f2bf(sTmp[t0][l]) | ((unsigned)f2bf(sTmp[t0 + 1][l]) << 16);
      *(unsigned*)(sXT + l * 64 + swz_idx(l, t0)) = pk;
    }
  }
  {  // mask + decay -> sGm
    int sr = w * 16 + ((l >> 4) << 2);
#pragma unroll
    for (int j = 0; j < 4; ++j) {
      int tc = j * 16 + (l & 15);
#pragma unroll
      for (int r = 0; r < 4; ++r) {
        int s = sr + r;
        float gv = (tc <= s) ? g4[j][r] * __expf(sL[s] - sL[tc]) : 0.f;
        sGm[s * 64 + swz_idx(s, tc)] = f2bf(gv);
      }
    }
  }
  __syncthreads();          // sXT + sGm ready
  // Y1[s][p] = Gm @ xs ; Hout[p][n] = xs^T . (ratio*B)
  f32x4 y1[4] = {}, ho[4] = {};
#pragma unroll
  for (int kh = 0; kh < 2; ++kh) {
    int cq = kh * 4 + (l >> 4);
    short8 agm = frag(sGm, w * 16 + (l & 15), cq);
    short8 axt = frag(sXT, w * 16 + (l & 15), cq);
#pragma unroll
    for (int j = 0; j < 4; ++j) {
      y1[j] = __builtin_amdgcn_mfma_f32_16x16x32_bf16(agm, frag(sXT, j * 16 + (l & 15), cq), y1[j], 0, 0, 0);
      ho[j] = __builtin_amdgcn_mfma_f32_16x16x32_bf16(axt, frag(sBT, j * 16 + (l & 15), cq), ho[j], 0, 0, 0);
    }
  }
  float* Hp = Hbuf + ((size_t)(bh * NCHUNK + c)) * 4096;
  int pr = w * 16 + ((l >> 4) << 2);
#pragma unroll
  for (int j = 0; j < 4; ++j)
#pragma unroll
    for (int r = 0; r < 4; ++r)
      Hp[(size_t)(pr + r) * 64 + j * 16 + (l & 15)] = ho[j][r];
#pragma unroll
  for (int r = 0; r < 4; ++r) {
    int s = pr + r;
#pragma unroll
    for (int j = 0; j < 4; ++j)
      y1b[(size_t)(m0 + s) * DINNER + h * 64 + j * 16 + (l & 15)] = y1[j][r];
  }
}

// ---------------- scan phase 2: element-parallel chunk recurrence ----------
__global__ __launch_bounds__(256) void scan2_kernel(
    float* __restrict__ Hbuf, const float* __restrict__ Lbuf) {
  int bh = blockIdx.x >> 4;
  int e = (blockIdx.x & 15) * 256 + threadIdx.x;
  int b = bh / NH, h = bh - b * NH;
  float S = 0.f;
  for (int c = 0; c < NCHUNK; ++c) {
    float* Hp = Hbuf + ((size_t)(bh * NCHUNK + c)) * 4096 + e;
    float P = __expf(Lbuf[(size_t)(b * SEQ + c * CLEN + CLEN - 1) * NH + h]);
    float v = *Hp;
    *Hp = S;
    S = P * S + v;
  }
}

// ---------------- scan kernel B: Y2 = C @ Hin^T (direct-global frags);
//   y = y1 + e^L * y2 + skip ; * silu(z) -> actb (bf16) ---------------------
__global__ __launch_bounds__(256) void scanB_kernel(
    const u16* __restrict__ proj, const float* __restrict__ Hbuf,
    const float* __restrict__ Lbuf, const float* __restrict__ skip_b,
    const float* __restrict__ y1b, u16* __restrict__ actb) {
  int c = blockIdx.x & 15, bh = blockIdx.x >> 4;
  int b = bh / NH, h = bh - b * NH;
  int t = threadIdx.x, w = t >> 6, l = t & 63;
  __shared__ float sL[64], sSkip[64];
  int m0 = b * SEQ + c * CLEN;
  if (w == 0) {
    sL[l] = Lbuf[(size_t)(m0 + l) * NH + h];
    sSkip[l] = skip_b[(size_t)(m0 + l) * NH + h];
  }
  const u16* baseC = proj + (size_t)m0 * PP + 4608 + h * 64;
  const float* Hp = Hbuf + ((size_t)(bh * NCHUNK + c)) * 4096;
  short8 cf[2], hf[2][4];
#pragma unroll
  for (int kh = 0; kh < 2; ++kh) {
    int cq = kh * 4 + (l >> 4);
    cf[kh] = *(const short8*)(baseC + (size_t)(w * 16 + (l & 15)) * PP + cq * 8);
#pragma unroll
    for (int j = 0; j < 4; ++j) {
      const float* hp = Hp + (size_t)(j * 16 + (l & 15)) * 64 + cq * 8;
      float4 a = *(const float4*)hp;
      float4 b2 = *(const float4*)(hp + 4);
      short8 hv;
      hv[0] = (short)f2bf(a.x);  hv[1] = (short)f2bf(a.y);
      hv[2] = (short)f2bf(a.z);  hv[3] = (short)f2bf(a.w);
      hv[4] = (short)f2bf(b2.x); hv[5] = (short)f2bf(b2.y);
      hv[6] = (short)f2bf(b2.z); hv[7] = (short)f2bf(b2.w);
      hf[kh][j] = hv;
    }
  }
  __syncthreads();
  f32x4 y2[4] = {};
#pragma unroll
  for (int kh = 0; kh < 2; ++kh)
#pragma unroll
    for (int j = 0; j < 4; ++j)
      y2[j] = __builtin_amdgcn_mfma_f32_16x16x32_bf16(cf[kh], hf[kh][j], y2[j], 0, 0, 0);
  int sr = w * 16 + ((l >> 4) << 2);
#pragma unroll
  for (int r = 0; r < 4; ++r) {
    int s = sr + r;
    float scale = __expf(sL[s]);
    float skp = sSkip[s];
    size_t mrow = (size_t)(m0 + s);
#pragma unroll
    for (int j = 0; j < 4; ++j) {
      int p = j * 16 + (l & 15);
      float y = y1b[mrow * DINNER + h * 64 + p] + scale * y2[j][r] + skp;
      float z = bf2f(proj[mrow * PP + h * 64 + p]);
      float sg = 1.f / (1.f + __expf(-z));
      actb[mrow * DINNER + h * 64 + p] = f2bf(y * z * sg);
    }
  }
}

extern "C" void kernel_launch(void* const* d_in, const int* in_sizes, int n_in,
                              void* d_out, int out_size, void* d_ws, size_t ws_size,
                              hipStream_t stream) {
  (void)in_sizes; (void)n_in; (void)out_size; (void)ws_size;
  const float* x      = (const float*)d_in[0];
  const float* n1w    = (const float*)d_in[1];
  const float* n2w    = (const float*)d_in[2];
  const float* w_in   = (const float*)d_in[3];
  const float* w_out  = (const float*)d_in[4];
  const float* A_log  = (const float*)d_in[5];
  const float* Dv     = (const float*)d_in[6];
  const float* dt_b   = (const float*)d_in[7];
  const float* B_bias = (const float*)d_in[8];
  const float* C_bias = (const float*)d_in[9];
  const float* Bnw    = (const float*)d_in[10];
  const float* Cnw    = (const float*)d_in[11];
  const float* w_g    = (const float*)d_in[12];
  const float* w_u    = (const float*)d_in[13];
  const float* w_d    = (const float*)d_in[14];
  float* out = (float*)d_out;

  char* ws = (char*)d_ws;
  size_t off = 0;
  auto alloc = [&](size_t bytes) -> char* {
    char* p = ws + off;
    off = (off + bytes + 255) & ~(size_t)255;
    return p;
  };
  u16*   wb_in  = (u16*)  alloc(E0 * 2);
  u16*   wb_out = (u16*)  alloc(E1 * 2);
  u16*   wb_gu  = (u16*)  alloc(E2 * 2 * 2);      // interleaved gate/up rows
  u16*   wb_d   = (u16*)  alloc(E2 * 2);
  u16*   h1     = (u16*)  alloc((size_t)MROWS * DMODEL * 2);
  u16*   proj   = (u16*)  alloc((size_t)MROWS * PP * 2);
  float* Abuf   = (float*)alloc((size_t)MROWS * NH * 4);
  float* skip_b = (float*)alloc((size_t)MROWS * NH * 4);
  float* Lbuf   = (float*)alloc((size_t)MROWS * NH * 4);
  float* dtheta = (float*)alloc((size_t)MROWS * 768 * 4);
  float* ctot   = (float*)alloc((size_t)B_N * NCHUNK * 768 * 4);
  float* Hbuf   = (float*)alloc((size_t)B_N * NH * NCHUNK * 4096 * 4);
  float* y1b    = (float*)alloc((size_t)MROWS * DINNER * 4);
  u16*   actb   = (u16*)  alloc((size_t)MROWS * DINNER * 2);
  float* tmp1   = (float*)alloc((size_t)MROWS * DMODEL * 4);
  float* x2     = (float*)alloc((size_t)MROWS * DMODEL * 4);
  u16*   h2     = (u16*)  alloc((size_t)MROWS * DMODEL * 2);
  u16*   gub    = (u16*)  alloc((size_t)MROWS * DMLP * 2);

  cast_all_kernel<<<(int)((ETOT / 4 + 255) / 256), 256, 0, stream>>>(
      w_in, w_out, w_g, w_u, w_d, wb_in, wb_out, wb_gu, wb_d);
  add_rmsnorm_kernel<<<MROWS, 256, 0, stream>>>(x, nullptr, n1w, nullptr, h1);
  {  // in_proj -> proj (bf16): 55 x 32 = 1760 blocks
    dim3 g(PP / 128, MROWS / 64);
    gemm_bt_kernel<64, 128, 1><<<g, 256, 0, stream>>>(h1, wb_in, proj, DMODEL, PP, nullptr);
  }
  prep_kernel<<<MROWS * NH / 4, 256, 0, stream>>>(proj, A_log, Dv, dt_b, B_bias, C_bias,
                                                  Bnw, Cnw, Abuf, skip_b, dtheta);
  cumsum_a_kernel<<<B_N * NCHUNK * 3, 256, 0, stream>>>(dtheta, ctot);
  cumsum_b_kernel<<<6, 256, 0, stream>>>(ctot);
  rope_kernel<<<MROWS * NH / 4, 256, 0, stream>>>(proj, dtheta, ctot);
  scanA_kernel<<<B_N * NH * NCHUNK, 256, 0, stream>>>(proj, Abuf, Lbuf, Hbuf, y1b);
  scan2_kernel<<<B_N * NH * NCHUNK, 256, 0, stream>>>(Hbuf, Lbuf);
  scanB_kernel<<<B_N * NH * NCHUNK, 256, 0, stream>>>(proj, Hbuf, Lbuf, skip_b, y1b, actb);
  {  // out_proj -> tmp1 (f32): 12 x 32 = 384 blocks
    dim3 g(DMODEL / 64, MROWS / 64);
    gemm_bt_kernel<64, 64, 0><<<g, 256, 0, stream>>>(actb, wb_out, tmp1, DINNER, DMODEL, nullptr);
  }
  add_rmsnorm_kernel<<<MROWS, 256, 0, stream>>>(x, tmp1, n2w, x2, h2);
  {  // gate+up fused GLU -> gub (bf16): 30 x 32 = 960 blocks
    dim3 g(2 * DMLP / 128, MROWS / 64);
    gemm_bt_kernel<64, 128, 2><<<g, 256, 0, stream>>>(h2, wb_gu, gub, DMODEL, DMLP, nullptr);
  }
  {  // down + residual -> out: 12 x 32 = 384 blocks
    dim3 g(DMODEL / 64, MROWS / 64);
    gemm_bt_kernel<64, 64, 0><<<g, 256, 0, stream>>>(gub, wb_d, out, DMLP, DMODEL, x2);
  }
}